// Round 1
// baseline (617.355 us; speedup 1.0000x reference)
//
#include <hip/hip_runtime.h>

typedef unsigned short ushort_t;
typedef unsigned int uint_t;
typedef __attribute__((ext_vector_type(8))) short bf16x8;
typedef __attribute__((ext_vector_type(4))) float f32x4;

#define B_ 4
#define C_ 256
#define I_ 128
#define N_ 4096

// workspace layout in ushort (bf16) elements
#define XT_HI 0ull
#define XT_LO 4194304ull
#define W_HI  8388608ull
#define W_LO  8519680ull
#define TH_HI 8650752ull
#define TH_LO 10747904ull
#define PH_HI 12845056ull
#define PH_LO 14942208ull
#define G_BF  17039360ull
#define Y_BF  0ull            // aliases XT_HI: x_t is dead before attention runs
// total 19136512 ushorts = 38,273,024 bytes

__device__ __forceinline__ ushort_t f2bf(float f) {
    uint_t u = __float_as_uint(f);
    uint_t r = u + 0x7fffu + ((u >> 16) & 1u);   // round-to-nearest-even
    return (ushort_t)(r >> 16);
}
__device__ __forceinline__ float bf2f(ushort_t h) {
    return __uint_as_float(((uint_t)h) << 16);
}
__device__ __forceinline__ f32x4 mfma16(bf16x8 a, bf16x8 b, f32x4 c) {
    return __builtin_amdgcn_mfma_f32_16x16x32_bf16(a, b, c, 0, 0, 0);
}
__device__ __forceinline__ f32x4 zero4() { f32x4 z = {0.f, 0.f, 0.f, 0.f}; return z; }

// ---------------- kernel 1: convert all weights to bf16 hi/lo ----------------
// w_g [128][256] @0, w_theta @32768, w_phi @65536, w_W [256][128] @98304
__global__ __launch_bounds__(256) void k_convert_w(const float* wg, const float* wt,
                                                   const float* wp, const float* wW,
                                                   ushort_t* ws) {
    int idx = blockIdx.x * 256 + threadIdx.x;   // 131072 total
    float v;
    if (idx < 32768)        v = wg[idx];
    else if (idx < 65536)   v = wt[idx - 32768];
    else if (idx < 98304)   v = wp[idx - 65536];
    else                    v = wW[idx - 98304];
    ushort_t h = f2bf(v);
    ws[W_HI + idx] = h;
    ws[W_LO + idx] = f2bf(v - bf2f(h));
}

// ---------------- kernel 2: transpose+convert x -> x_t [B][N][C] hi/lo -------
__global__ __launch_bounds__(256) void k_transpose_x(const float* x, ushort_t* ws) {
    __shared__ float t[64][65];
    int b = blockIdx.z, c0 = blockIdx.y * 64, n0 = blockIdx.x * 64;
    int tid = threadIdx.x;
    int cl = tid & 63, ng = tid >> 6;
    const float* xp = x + ((size_t)(b * C_ + c0 + cl)) * N_ + n0 + ng * 16;
#pragma unroll
    for (int j = 0; j < 4; ++j) {
        float4 v = ((const float4*)xp)[j];
        t[cl][ng * 16 + j * 4 + 0] = v.x;
        t[cl][ng * 16 + j * 4 + 1] = v.y;
        t[cl][ng * 16 + j * 4 + 2] = v.z;
        t[cl][ng * 16 + j * 4 + 3] = v.w;
    }
    __syncthreads();
    int nl = tid & 63, cg = tid >> 6;
    ushort_t hh[16], ll[16];
#pragma unroll
    for (int k = 0; k < 16; ++k) {
        float v = t[cg * 16 + k][nl];
        ushort_t h = f2bf(v);
        hh[k] = h;
        ll[k] = f2bf(v - bf2f(h));
    }
    size_t dst = ((size_t)b * N_ + n0 + nl) * C_ + c0 + cg * 16;
    *(uint4*)&ws[XT_HI + dst]     = *(uint4*)&hh[0];
    *(uint4*)&ws[XT_HI + dst + 8] = *(uint4*)&hh[8];
    *(uint4*)&ws[XT_LO + dst]     = *(uint4*)&ll[0];
    *(uint4*)&ws[XT_LO + dst + 8] = *(uint4*)&ll[8];
}

// ------- kernel 3: theta/phi projections, written directly as [B][N][I] ------
// M-dim = n (A = x_t), N-dim = i (B = w rows). out = x W^T + bias, hi/lo split.
__global__ __launch_bounds__(256) void k_proj_T(const float* bth, const float* bph,
                                                ushort_t* ws) {
    int b = blockIdx.y, proj = blockIdx.z;
    int w = threadIdx.x >> 6, l = threadIdx.x & 63;
    int n_base = blockIdx.x * 64 + w * 16;
    const ushort_t* wh = ws + W_HI + (size_t)(1 + proj) * 32768;
    const ushort_t* wl = ws + W_LO + (size_t)(1 + proj) * 32768;
    const ushort_t* xh = ws + XT_HI;
    const ushort_t* xl = ws + XT_LO;
    const float* bias = proj ? bph : bth;

    f32x4 acc[8];
#pragma unroll
    for (int i = 0; i < 8; ++i) acc[i] = zero4();

    int arow = n_base + (l & 15);
#pragma unroll 2
    for (int kb = 0; kb < 8; ++kb) {
        int kc = kb * 32 + 8 * (l >> 4);
        bf16x8 a_h = *(const bf16x8*)&xh[((size_t)b * N_ + arow) * C_ + kc];
        bf16x8 a_l = *(const bf16x8*)&xl[((size_t)b * N_ + arow) * C_ + kc];
#pragma unroll
        for (int i16 = 0; i16 < 8; ++i16) {
            bf16x8 b_h = *(const bf16x8*)&wh[(size_t)(i16 * 16 + (l & 15)) * C_ + kc];
            bf16x8 b_l = *(const bf16x8*)&wl[(size_t)(i16 * 16 + (l & 15)) * C_ + kc];
            acc[i16] = mfma16(a_h, b_h, acc[i16]);
            acc[i16] = mfma16(a_h, b_l, acc[i16]);
            acc[i16] = mfma16(a_l, b_h, acc[i16]);
        }
    }
    ushort_t* th = ws + (proj ? PH_HI : TH_HI);
    ushort_t* tl = ws + (proj ? PH_LO : TH_LO);
#pragma unroll
    for (int i16 = 0; i16 < 8; ++i16) {
#pragma unroll
        for (int r = 0; r < 4; ++r) {
            float v = acc[i16][r] + bias[i16 * 16 + (l & 15)];
            int n = n_base + (l >> 4) * 4 + r;
            size_t di = ((size_t)b * N_ + n) * I_ + i16 * 16 + (l & 15);
            ushort_t h = f2bf(v);
            th[di] = h;
            tl[di] = f2bf(v - bf2f(h));
        }
    }
}

// ---------------- kernel 4: g projection -> [B][I][N] bf16 -------------------
__global__ __launch_bounds__(256) void k_proj_G(const float* bg, ushort_t* ws) {
    int b = blockIdx.y, n0 = blockIdx.x * 64;
    int w = threadIdx.x >> 6, l = threadIdx.x & 63;
    int ih = (w >> 1) * 64, nh = (w & 1) * 32;
    const ushort_t* wh = ws + W_HI;   // w_g at offset 0
    const ushort_t* wl = ws + W_LO;
    const ushort_t* xh = ws + XT_HI;
    const ushort_t* xl = ws + XT_LO;

    f32x4 acc[4][2];
#pragma unroll
    for (int m = 0; m < 4; ++m)
#pragma unroll
        for (int n = 0; n < 2; ++n) acc[m][n] = zero4();

#pragma unroll 2
    for (int kb = 0; kb < 8; ++kb) {
        int kc = kb * 32 + 8 * (l >> 4);
        bf16x8 ah[4], al[4], bh[2], bl[2];
#pragma unroll
        for (int m = 0; m < 4; ++m) {
            ah[m] = *(const bf16x8*)&wh[(size_t)(ih + m * 16 + (l & 15)) * C_ + kc];
            al[m] = *(const bf16x8*)&wl[(size_t)(ih + m * 16 + (l & 15)) * C_ + kc];
        }
#pragma unroll
        for (int n = 0; n < 2; ++n) {
            size_t row = (size_t)b * N_ + n0 + nh + n * 16 + (l & 15);
            bh[n] = *(const bf16x8*)&xh[row * C_ + kc];
            bl[n] = *(const bf16x8*)&xl[row * C_ + kc];
        }
#pragma unroll
        for (int m = 0; m < 4; ++m)
#pragma unroll
            for (int n = 0; n < 2; ++n) {
                acc[m][n] = mfma16(ah[m], bh[n], acc[m][n]);
                acc[m][n] = mfma16(ah[m], bl[n], acc[m][n]);
                acc[m][n] = mfma16(al[m], bh[n], acc[m][n]);
            }
    }
#pragma unroll
    for (int m = 0; m < 4; ++m)
#pragma unroll
        for (int n = 0; n < 2; ++n)
#pragma unroll
            for (int r = 0; r < 4; ++r) {
                int i = ih + m * 16 + (l >> 4) * 4 + r;
                int nn = n0 + nh + n * 16 + (l & 15);
                float v = acc[m][n][r] + bg[i];
                ws[G_BF + ((size_t)b * I_ + i) * N_ + nn] = f2bf(v);
            }
}

// ---------------- kernel 5: flash attention ----------------------------------
// grid (64 qtiles, B). 4 waves/block, 16 q-rows/wave, KVBLK=32.
__global__ __launch_bounds__(256) void k_attn(ushort_t* ws) {
    int b = blockIdx.y;
    int w = threadIdx.x >> 6, l = threadIdx.x & 63;
    int q0 = blockIdx.x * 64 + w * 16;
    const ushort_t* th = ws + TH_HI;
    const ushort_t* tl = ws + TH_LO;
    const ushort_t* ph = ws + PH_HI;
    const ushort_t* pl = ws + PH_LO;
    const ushort_t* g  = ws + G_BF;
    ushort_t* yb = ws + Y_BF;

    __shared__ ushort_t P[4][16][56];   // 112B rows: 16B-aligned b128, <=2-way bank

    // Q fragments (hi/lo), K=128 in 4 chunks of 32
    bf16x8 qh[4], ql[4];
#pragma unroll
    for (int kb = 0; kb < 4; ++kb) {
        size_t qi = ((size_t)b * N_ + q0 + (l & 15)) * I_ + kb * 32 + 8 * (l >> 4);
        qh[kb] = *(const bf16x8*)&th[qi];
        ql[kb] = *(const bf16x8*)&tl[qi];
    }

    f32x4 y[8];
#pragma unroll
    for (int dt = 0; dt < 8; ++dt) y[dt] = zero4();
    float m[4], ls[4];
#pragma unroll
    for (int r = 0; r < 4; ++r) { m[r] = -1e30f; ls[r] = 0.f; }

    for (int kv0 = 0; kv0 < N_; kv0 += 32) {
        f32x4 f0 = zero4(), f1 = zero4();
#pragma unroll
        for (int kb = 0; kb < 4; ++kb) {
            int kc = kb * 32 + 8 * (l >> 4);
            size_t r0 = ((size_t)b * N_ + kv0 + (l & 15)) * I_ + kc;
            size_t r1 = ((size_t)b * N_ + kv0 + 16 + (l & 15)) * I_ + kc;
            bf16x8 b0h = *(const bf16x8*)&ph[r0];
            bf16x8 b0l = *(const bf16x8*)&pl[r0];
            bf16x8 b1h = *(const bf16x8*)&ph[r1];
            bf16x8 b1l = *(const bf16x8*)&pl[r1];
            f0 = mfma16(qh[kb], b0h, f0);
            f0 = mfma16(qh[kb], b0l, f0);
            f0 = mfma16(ql[kb], b0h, f0);
            f1 = mfma16(qh[kb], b1h, f1);
            f1 = mfma16(qh[kb], b1l, f1);
            f1 = mfma16(ql[kb], b1h, f1);
        }
        // row max (over 16 cols held across the 16-lane group)
        float tm[4];
#pragma unroll
        for (int r = 0; r < 4; ++r) tm[r] = fmaxf(f0[r], f1[r]);
#pragma unroll
        for (int mk = 1; mk <= 8; mk <<= 1)
#pragma unroll
            for (int r = 0; r < 4; ++r) tm[r] = fmaxf(tm[r], __shfl_xor(tm[r], mk));
        // defer-max (T13): only rescale when the max grew by > 8
        bool need = false;
#pragma unroll
        for (int r = 0; r < 4; ++r) need = need || (tm[r] > m[r] + 8.f);
        if (__ballot(need)) {
#pragma unroll
            for (int r = 0; r < 4; ++r) {
                float mn = fmaxf(m[r], tm[r]);
                float sc = __expf(m[r] - mn);
                ls[r] *= sc;
                m[r] = mn;
#pragma unroll
                for (int dt = 0; dt < 8; ++dt) y[dt][r] *= sc;
            }
        }
        float p0[4], p1[4], rs[4];
#pragma unroll
        for (int r = 0; r < 4; ++r) {
            p0[r] = __expf(f0[r] - m[r]);
            p1[r] = __expf(f1[r] - m[r]);
            rs[r] = p0[r] + p1[r];
        }
#pragma unroll
        for (int mk = 1; mk <= 8; mk <<= 1)
#pragma unroll
            for (int r = 0; r < 4; ++r) rs[r] += __shfl_xor(rs[r], mk);
#pragma unroll
        for (int r = 0; r < 4; ++r) ls[r] += rs[r];
        // P -> LDS (D-layout scatter), then re-read as A-fragment
        int pr = (l >> 4) * 4, pc = l & 15;
#pragma unroll
        for (int r = 0; r < 4; ++r) {
            P[w][pr + r][pc]      = f2bf(p0[r]);
            P[w][pr + r][16 + pc] = f2bf(p1[r]);
        }
        bf16x8 pa = *(const bf16x8*)&P[w][l & 15][8 * (l >> 4)];
#pragma unroll
        for (int dt = 0; dt < 8; ++dt) {
            size_t gi = ((size_t)b * I_ + dt * 16 + (l & 15)) * N_ + kv0 + 8 * (l >> 4);
            bf16x8 vg = *(const bf16x8*)&g[gi];
            y[dt] = mfma16(pa, vg, y[dt]);
        }
    }
#pragma unroll
    for (int r = 0; r < 4; ++r) {
        float inv = 1.0f / ls[r];
#pragma unroll
        for (int dt = 0; dt < 8; ++dt) {
            float v = y[dt][r] * inv;
            yb[((size_t)b * N_ + q0 + (l >> 4) * 4 + r) * I_ + dt * 16 + (l & 15)] = f2bf(v);
        }
    }
}

// ---------------- kernel 6: output projection + residual ---------------------
__global__ __launch_bounds__(256) void k_out(const float* x, const float* bW,
                                             const ushort_t* ws, float* out) {
    int b = blockIdx.y, n0 = blockIdx.x * 64;
    int w = threadIdx.x >> 6, l = threadIdx.x & 63;
    int cw = blockIdx.z * 128 + (w >> 1) * 64;
    int nh = (w & 1) * 32;
    const ushort_t* wh = ws + W_HI + 98304;   // w_W [256][128]
    const ushort_t* wl = ws + W_LO + 98304;
    const ushort_t* yb = ws + Y_BF;

    f32x4 acc[4][2];
#pragma unroll
    for (int m = 0; m < 4; ++m)
#pragma unroll
        for (int n = 0; n < 2; ++n) acc[m][n] = zero4();

#pragma unroll 2
    for (int kb = 0; kb < 4; ++kb) {
        int kc = kb * 32 + 8 * (l >> 4);
        bf16x8 ah[4], al[4], by[2];
#pragma unroll
        for (int m = 0; m < 4; ++m) {
            ah[m] = *(const bf16x8*)&wh[(size_t)(cw + m * 16 + (l & 15)) * I_ + kc];
            al[m] = *(const bf16x8*)&wl[(size_t)(cw + m * 16 + (l & 15)) * I_ + kc];
        }
#pragma unroll
        for (int n = 0; n < 2; ++n)
            by[n] = *(const bf16x8*)&yb[((size_t)b * N_ + n0 + nh + n * 16 + (l & 15)) * I_ + kc];
#pragma unroll
        for (int m = 0; m < 4; ++m)
#pragma unroll
            for (int n = 0; n < 2; ++n) {
                acc[m][n] = mfma16(ah[m], by[n], acc[m][n]);
                acc[m][n] = mfma16(al[m], by[n], acc[m][n]);
            }
    }
#pragma unroll
    for (int m = 0; m < 4; ++m)
#pragma unroll
        for (int n = 0; n < 2; ++n)
#pragma unroll
            for (int r = 0; r < 4; ++r) {
                int c = cw + m * 16 + (l >> 4) * 4 + r;
                int nn = n0 + nh + n * 16 + (l & 15);
                size_t xi = ((size_t)b * C_ + c) * N_ + nn;
                out[xi] = acc[m][n][r] + bW[c] + x[xi];
            }
}

extern "C" void kernel_launch(void* const* d_in, const int* in_sizes, int n_in,
                              void* d_out, int out_size, void* d_ws, size_t ws_size,
                              hipStream_t stream) {
    const float* x  = (const float*)d_in[0];
    const float* wg = (const float*)d_in[1];
    const float* bg = (const float*)d_in[2];
    const float* wt = (const float*)d_in[3];
    const float* bt = (const float*)d_in[4];
    const float* wp = (const float*)d_in[5];
    const float* bp = (const float*)d_in[6];
    const float* wW = (const float*)d_in[7];
    const float* bW = (const float*)d_in[8];
    ushort_t* ws = (ushort_t*)d_ws;
    float* out = (float*)d_out;

    k_convert_w<<<512, 256, 0, stream>>>(wg, wt, wp, wW, ws);
    k_transpose_x<<<dim3(64, 4, 4), 256, 0, stream>>>(x, ws);
    k_proj_T<<<dim3(64, 4, 2), 256, 0, stream>>>(bt, bp, ws);
    k_proj_G<<<dim3(64, 4), 256, 0, stream>>>(bg, ws);
    k_attn<<<dim3(64, 4), 256, 0, stream>>>(ws);
    k_out<<<dim3(64, 4, 2), 256, 0, stream>>>(x, bW, ws, out);
}

// Round 2
// 546.486 us; speedup vs baseline: 1.1297x; 1.1297x over previous
//
#include <hip/hip_runtime.h>

typedef unsigned short ushort_t;
typedef unsigned int uint_t;
typedef __attribute__((ext_vector_type(8))) short bf16x8;
typedef __attribute__((ext_vector_type(4))) float f32x4;

#define B_ 4
#define C_ 256
#define I_ 128
#define N_ 4096
#define SPLITS 4
#define KV_PER (N_ / SPLITS)

// workspace layout in ushort (bf16) elements
#define XT_HI 0ull
#define XT_LO 4194304ull
#define W_HI  8388608ull
#define W_LO  8519680ull
#define TH_HI 8650752ull
#define TH_LO 10747904ull
#define PH_HI 12845056ull
#define PH_LO 14942208ull
#define G_BF  17039360ull
// attention partials: yp [S][B][N][I] bf16 aliases XT_HI..XT_LO (x_t dead);
// merged y bf16 goes to TH_HI (theta dead after attn; kernels serialize on stream)
#define YP_OFF 0ull
#define YM_OFF TH_HI
// lse [S][B][N] f32 appended after G region
#define LSE_BYTE_OFF 38273024ull
// total ws usage ~39.3 MB

__device__ __forceinline__ ushort_t f2bf(float f) {
    uint_t u = __float_as_uint(f);
    uint_t r = u + 0x7fffu + ((u >> 16) & 1u);   // round-to-nearest-even
    return (ushort_t)(r >> 16);
}
__device__ __forceinline__ float bf2f(ushort_t h) {
    return __uint_as_float(((uint_t)h) << 16);
}
__device__ __forceinline__ uint_t cvtpk(float lo, float hi) {
    uint_t r;
    asm volatile("v_cvt_pk_bf16_f32 %0, %1, %2" : "=v"(r) : "v"(lo), "v"(hi));
    return r;
}
__device__ __forceinline__ f32x4 mfma16(bf16x8 a, bf16x8 b, f32x4 c) {
    return __builtin_amdgcn_mfma_f32_16x16x32_bf16(a, b, c, 0, 0, 0);
}
__device__ __forceinline__ f32x4 zero4() { f32x4 z = {0.f, 0.f, 0.f, 0.f}; return z; }

// ---------------- kernel 1: convert all weights to bf16 hi/lo ----------------
__global__ __launch_bounds__(256) void k_convert_w(const float* wg, const float* wt,
                                                   const float* wp, const float* wW,
                                                   ushort_t* ws) {
    int idx = blockIdx.x * 256 + threadIdx.x;   // 131072 total
    float v;
    if (idx < 32768)        v = wg[idx];
    else if (idx < 65536)   v = wt[idx - 32768];
    else if (idx < 98304)   v = wp[idx - 65536];
    else                    v = wW[idx - 98304];
    ushort_t h = f2bf(v);
    ws[W_HI + idx] = h;
    ws[W_LO + idx] = f2bf(v - bf2f(h));
}

// ---------------- kernel 2: transpose+convert x -> x_t [B][N][C] hi/lo -------
__global__ __launch_bounds__(256) void k_transpose_x(const float* x, ushort_t* ws) {
    __shared__ float t[64][65];
    int b = blockIdx.z, c0 = blockIdx.y * 64, n0 = blockIdx.x * 64;
    int tid = threadIdx.x;
    int cl = tid & 63, ng = tid >> 6;
    const float* xp = x + ((size_t)(b * C_ + c0 + cl)) * N_ + n0 + ng * 16;
#pragma unroll
    for (int j = 0; j < 4; ++j) {
        float4 v = ((const float4*)xp)[j];
        t[cl][ng * 16 + j * 4 + 0] = v.x;
        t[cl][ng * 16 + j * 4 + 1] = v.y;
        t[cl][ng * 16 + j * 4 + 2] = v.z;
        t[cl][ng * 16 + j * 4 + 3] = v.w;
    }
    __syncthreads();
    int nl = tid & 63, cg = tid >> 6;
    ushort_t hh[16], ll[16];
#pragma unroll
    for (int k = 0; k < 16; ++k) {
        float v = t[cg * 16 + k][nl];
        ushort_t h = f2bf(v);
        hh[k] = h;
        ll[k] = f2bf(v - bf2f(h));
    }
    size_t dst = ((size_t)b * N_ + n0 + nl) * C_ + c0 + cg * 16;
    *(uint4*)&ws[XT_HI + dst]     = *(uint4*)&hh[0];
    *(uint4*)&ws[XT_HI + dst + 8] = *(uint4*)&hh[8];
    *(uint4*)&ws[XT_LO + dst]     = *(uint4*)&ll[0];
    *(uint4*)&ws[XT_LO + dst + 8] = *(uint4*)&ll[8];
}

// ------- kernel 3: theta/phi projections, written directly as [B][N][I] ------
__global__ __launch_bounds__(256) void k_proj_T(const float* bth, const float* bph,
                                                ushort_t* ws) {
    int b = blockIdx.y, proj = blockIdx.z;
    int w = threadIdx.x >> 6, l = threadIdx.x & 63;
    int n_base = blockIdx.x * 64 + w * 16;
    const ushort_t* wh = ws + W_HI + (size_t)(1 + proj) * 32768;
    const ushort_t* wl = ws + W_LO + (size_t)(1 + proj) * 32768;
    const ushort_t* xh = ws + XT_HI;
    const ushort_t* xl = ws + XT_LO;
    const float* bias = proj ? bph : bth;

    f32x4 acc[8];
#pragma unroll
    for (int i = 0; i < 8; ++i) acc[i] = zero4();

    int arow = n_base + (l & 15);
#pragma unroll 2
    for (int kb = 0; kb < 8; ++kb) {
        int kc = kb * 32 + 8 * (l >> 4);
        bf16x8 a_h = *(const bf16x8*)&xh[((size_t)b * N_ + arow) * C_ + kc];
        bf16x8 a_l = *(const bf16x8*)&xl[((size_t)b * N_ + arow) * C_ + kc];
#pragma unroll
        for (int i16 = 0; i16 < 8; ++i16) {
            bf16x8 b_h = *(const bf16x8*)&wh[(size_t)(i16 * 16 + (l & 15)) * C_ + kc];
            bf16x8 b_l = *(const bf16x8*)&wl[(size_t)(i16 * 16 + (l & 15)) * C_ + kc];
            acc[i16] = mfma16(a_h, b_h, acc[i16]);
            acc[i16] = mfma16(a_h, b_l, acc[i16]);
            acc[i16] = mfma16(a_l, b_h, acc[i16]);
        }
    }
    ushort_t* th = ws + (proj ? PH_HI : TH_HI);
    ushort_t* tl = ws + (proj ? PH_LO : TH_LO);
#pragma unroll
    for (int i16 = 0; i16 < 8; ++i16) {
#pragma unroll
        for (int r = 0; r < 4; ++r) {
            float v = acc[i16][r] + bias[i16 * 16 + (l & 15)];
            int n = n_base + (l >> 4) * 4 + r;
            size_t di = ((size_t)b * N_ + n) * I_ + i16 * 16 + (l & 15);
            ushort_t h = f2bf(v);
            th[di] = h;
            tl[di] = f2bf(v - bf2f(h));
        }
    }
}

// ---------------- kernel 4: g projection -> [B][I][N] bf16 -------------------
__global__ __launch_bounds__(256) void k_proj_G(const float* bg, ushort_t* ws) {
    int b = blockIdx.y, n0 = blockIdx.x * 64;
    int w = threadIdx.x >> 6, l = threadIdx.x & 63;
    int ih = (w >> 1) * 64, nh = (w & 1) * 32;
    const ushort_t* wh = ws + W_HI;
    const ushort_t* wl = ws + W_LO;
    const ushort_t* xh = ws + XT_HI;
    const ushort_t* xl = ws + XT_LO;

    f32x4 acc[4][2];
#pragma unroll
    for (int m = 0; m < 4; ++m)
#pragma unroll
        for (int n = 0; n < 2; ++n) acc[m][n] = zero4();

#pragma unroll 2
    for (int kb = 0; kb < 8; ++kb) {
        int kc = kb * 32 + 8 * (l >> 4);
        bf16x8 ah[4], al[4], bh[2], bl[2];
#pragma unroll
        for (int m = 0; m < 4; ++m) {
            ah[m] = *(const bf16x8*)&wh[(size_t)(ih + m * 16 + (l & 15)) * C_ + kc];
            al[m] = *(const bf16x8*)&wl[(size_t)(ih + m * 16 + (l & 15)) * C_ + kc];
        }
#pragma unroll
        for (int n = 0; n < 2; ++n) {
            size_t row = (size_t)b * N_ + n0 + nh + n * 16 + (l & 15);
            bh[n] = *(const bf16x8*)&xh[row * C_ + kc];
            bl[n] = *(const bf16x8*)&xl[row * C_ + kc];
        }
#pragma unroll
        for (int m = 0; m < 4; ++m)
#pragma unroll
            for (int n = 0; n < 2; ++n) {
                acc[m][n] = mfma16(ah[m], bh[n], acc[m][n]);
                acc[m][n] = mfma16(ah[m], bl[n], acc[m][n]);
                acc[m][n] = mfma16(al[m], bh[n], acc[m][n]);
            }
    }
#pragma unroll
    for (int m = 0; m < 4; ++m)
#pragma unroll
        for (int n = 0; n < 2; ++n)
#pragma unroll
            for (int r = 0; r < 4; ++r) {
                int i = ih + m * 16 + (l >> 4) * 4 + r;
                int nn = n0 + nh + n * 16 + (l & 15);
                float v = acc[m][n][r] + bg[i];
                ws[G_BF + ((size_t)b * I_ + i) * N_ + nn] = f2bf(v);
            }
}

// ---------------- kernel 5: flash attention, split-KV, swapped QK^T ----------
// grid (64 qtiles, B, SPLITS). 4 waves/block, 16 q-rows/wave, KVBLK=32.
// QK^T computed as mfma(phi, theta): D row = kv, col = q -> P is lane-local
// per q row (q = lane&15, replicated over lane>>4). PV feeds P in-register via
// a custom (lane,j)->kv map used consistently on A (P) and B (g) operands.
__global__ __launch_bounds__(256, 4) void k_attn(ushort_t* ws, float* lse) {
    int b = blockIdx.y, sp = blockIdx.z;
    int w = threadIdx.x >> 6, l = threadIdx.x & 63;
    int li = l & 15, lg = l >> 4;
    int q0 = blockIdx.x * 64 + w * 16;
    const ushort_t* th = ws + TH_HI;
    const ushort_t* tl = ws + TH_LO;
    const ushort_t* ph = ws + PH_HI;
    const ushort_t* pl = ws + PH_LO;
    const ushort_t* g  = ws + G_BF;
    ushort_t* yp = ws + YP_OFF + (size_t)sp * ((size_t)B_ * N_ * I_);

    // Q fragments (hi/lo) as B-operand: b[j] = theta[q0+li][kb*32 + 8*lg + j]
    bf16x8 qh[4], ql[4];
#pragma unroll
    for (int kb = 0; kb < 4; ++kb) {
        size_t qi = ((size_t)b * N_ + q0 + li) * I_ + kb * 32 + 8 * lg;
        qh[kb] = *(const bf16x8*)&th[qi];
        ql[kb] = *(const bf16x8*)&tl[qi];
    }

    f32x4 y[8];
#pragma unroll
    for (int dt = 0; dt < 8; ++dt) y[dt] = zero4();
    float m = -1e30f, ls = 0.f;

    int kv_beg = sp * KV_PER, kv_end = kv_beg + KV_PER;
    for (int kv0 = kv_beg; kv0 < kv_end; kv0 += 32) {
        f32x4 f0 = zero4(), f1 = zero4();
        size_t r0 = ((size_t)b * N_ + kv0 + li) * I_;
        size_t r1 = r0 + (size_t)16 * I_;
#pragma unroll
        for (int kb = 0; kb < 4; ++kb) {
            int kc = kb * 32 + 8 * lg;
            bf16x8 a0h = *(const bf16x8*)&ph[r0 + kc];
            bf16x8 a0l = *(const bf16x8*)&pl[r0 + kc];
            bf16x8 a1h = *(const bf16x8*)&ph[r1 + kc];
            bf16x8 a1l = *(const bf16x8*)&pl[r1 + kc];
            f0 = mfma16(a0h, qh[kb], f0);
            f0 = mfma16(a0h, ql[kb], f0);
            f0 = mfma16(a0l, qh[kb], f0);
            f1 = mfma16(a1h, qh[kb], f1);
            f1 = mfma16(a1h, ql[kb], f1);
            f1 = mfma16(a1l, qh[kb], f1);
        }
        // row max: in-lane over 8 + 2 cross-group shuffles
        float tm = fmaxf(fmaxf(fmaxf(f0[0], f0[1]), fmaxf(f0[2], f0[3])),
                         fmaxf(fmaxf(f1[0], f1[1]), fmaxf(f1[2], f1[3])));
        tm = fmaxf(tm, __shfl_xor(tm, 16));
        tm = fmaxf(tm, __shfl_xor(tm, 32));
        // defer-max (T13)
        if (__ballot(tm > m + 8.f)) {
            float mn = fmaxf(m, tm);
            float sc = __expf(m - mn);
            ls *= sc; m = mn;
            float s0 = __shfl(sc, 4 * lg + 0);
            float s1 = __shfl(sc, 4 * lg + 1);
            float s2 = __shfl(sc, 4 * lg + 2);
            float s3 = __shfl(sc, 4 * lg + 3);
#pragma unroll
            for (int dt = 0; dt < 8; ++dt) {
                y[dt][0] *= s0; y[dt][1] *= s1; y[dt][2] *= s2; y[dt][3] *= s3;
            }
        }
        float p00 = __expf(f0[0] - m), p01 = __expf(f0[1] - m);
        float p02 = __expf(f0[2] - m), p03 = __expf(f0[3] - m);
        float p10 = __expf(f1[0] - m), p11 = __expf(f1[1] - m);
        float p12 = __expf(f1[2] - m), p13 = __expf(f1[3] - m);
        float rs = ((p00 + p01) + (p02 + p03)) + ((p10 + p11) + (p12 + p13));
        rs += __shfl_xor(rs, 16);
        rs += __shfl_xor(rs, 32);
        ls += rs;
        // pack P as PV A-operand: a[j] = P[q=li][kv: j<4 -> 4lg+j, j>=4 -> 16+4lg+(j-4)]
        union { uint_t u[4]; bf16x8 v; } pu;
        pu.u[0] = cvtpk(p00, p01);
        pu.u[1] = cvtpk(p02, p03);
        pu.u[2] = cvtpk(p10, p11);
        pu.u[3] = cvtpk(p12, p13);
#pragma unroll
        for (int dt = 0; dt < 8; ++dt) {
            size_t grow = ((size_t)b * I_ + dt * 16 + li) * N_ + kv0 + 4 * lg;
            uint2 ga = *(const uint2*)&g[grow];
            uint2 gb = *(const uint2*)&g[grow + 16];
            union { uint_t u[4]; bf16x8 v; } gu;
            gu.u[0] = ga.x; gu.u[1] = ga.y; gu.u[2] = gb.x; gu.u[3] = gb.y;
            y[dt] = mfma16(pu.v, gu.v, y[dt]);
        }
    }
    // epilogue: normalized partial + lse
    float inv = 1.0f / ls;
    float i0 = __shfl(inv, 4 * lg + 0);
    float i1 = __shfl(inv, 4 * lg + 1);
    float i2 = __shfl(inv, 4 * lg + 2);
    float i3 = __shfl(inv, 4 * lg + 3);
#pragma unroll
    for (int dt = 0; dt < 8; ++dt) {
        size_t base = ((size_t)b * N_ + q0 + 4 * lg) * I_ + dt * 16 + li;
        yp[base]            = f2bf(y[dt][0] * i0);
        yp[base + I_]       = f2bf(y[dt][1] * i1);
        yp[base + 2 * I_]   = f2bf(y[dt][2] * i2);
        yp[base + 3 * I_]   = f2bf(y[dt][3] * i3);
    }
    if (l < 16)
        lse[((size_t)sp * B_ + b) * N_ + q0 + l] = m + __logf(ls);
}

// ---------------- kernel 5b: merge split-KV partials -------------------------
__global__ __launch_bounds__(256) void k_merge(ushort_t* ws, const float* lse) {
    int t = blockIdx.x * 256 + threadIdx.x;     // 1024 blocks -> B*N*I/8 threads
    size_t base = (size_t)t * 8;
    size_t row = base >> 7;                     // / I_
    float l0 = lse[row];
    float l1 = lse[(size_t)B_ * N_ + row];
    float l2 = lse[2 * (size_t)B_ * N_ + row];
    float l3 = lse[3 * (size_t)B_ * N_ + row];
    float mx = fmaxf(fmaxf(l0, l1), fmaxf(l2, l3));
    float w0 = __expf(l0 - mx), w1 = __expf(l1 - mx);
    float w2 = __expf(l2 - mx), w3 = __expf(l3 - mx);
    float inv = 1.0f / (w0 + w1 + w2 + w3);
    w0 *= inv; w1 *= inv; w2 *= inv; w3 *= inv;
    const ushort_t* yp = ws + YP_OFF;
    const size_t STRIDE = (size_t)B_ * N_ * I_;
    float acc[8];
#pragma unroll
    for (int j = 0; j < 8; ++j) acc[j] = 0.f;
    float wgt[4] = {w0, w1, w2, w3};
#pragma unroll
    for (int sp = 0; sp < 4; ++sp) {
        bf16x8 v = *(const bf16x8*)&yp[sp * STRIDE + base];
#pragma unroll
        for (int j = 0; j < 8; ++j) acc[j] += wgt[sp] * bf2f((ushort_t)v[j]);
    }
    ushort_t o[8];
#pragma unroll
    for (int j = 0; j < 8; ++j) o[j] = f2bf(acc[j]);
    *(uint4*)&ws[YM_OFF + base] = *(uint4*)&o[0];
}

// ---------------- kernel 6: output projection + residual ---------------------
__global__ __launch_bounds__(256) void k_out(const float* x, const float* bW,
                                             const ushort_t* ws, float* out) {
    int b = blockIdx.y, n0 = blockIdx.x * 64;
    int w = threadIdx.x >> 6, l = threadIdx.x & 63;
    int cw = blockIdx.z * 128 + (w >> 1) * 64;
    int nh = (w & 1) * 32;
    const ushort_t* wh = ws + W_HI + 98304;   // w_W [256][128]
    const ushort_t* wl = ws + W_LO + 98304;
    const ushort_t* yb = ws + YM_OFF;

    f32x4 acc[4][2];
#pragma unroll
    for (int m = 0; m < 4; ++m)
#pragma unroll
        for (int n = 0; n < 2; ++n) acc[m][n] = zero4();

#pragma unroll 2
    for (int kb = 0; kb < 4; ++kb) {
        int kc = kb * 32 + 8 * (l >> 4);
        bf16x8 ah[4], al[4], by[2];
#pragma unroll
        for (int m = 0; m < 4; ++m) {
            ah[m] = *(const bf16x8*)&wh[(size_t)(cw + m * 16 + (l & 15)) * I_ + kc];
            al[m] = *(const bf16x8*)&wl[(size_t)(cw + m * 16 + (l & 15)) * I_ + kc];
        }
#pragma unroll
        for (int n = 0; n < 2; ++n)
            by[n] = *(const bf16x8*)&yb[((size_t)b * N_ + n0 + nh + n * 16 + (l & 15)) * I_ + kc];
#pragma unroll
        for (int m = 0; m < 4; ++m)
#pragma unroll
            for (int n = 0; n < 2; ++n) {
                acc[m][n] = mfma16(ah[m], by[n], acc[m][n]);
                acc[m][n] = mfma16(al[m], by[n], acc[m][n]);
            }
    }
#pragma unroll
    for (int m = 0; m < 4; ++m)
#pragma unroll
        for (int n = 0; n < 2; ++n)
#pragma unroll
            for (int r = 0; r < 4; ++r) {
                int c = cw + m * 16 + (l >> 4) * 4 + r;
                int nn = n0 + nh + n * 16 + (l & 15);
                size_t xi = ((size_t)b * C_ + c) * N_ + nn;
                out[xi] = acc[m][n][r] + bW[c] + x[xi];
            }
}

extern "C" void kernel_launch(void* const* d_in, const int* in_sizes, int n_in,
                              void* d_out, int out_size, void* d_ws, size_t ws_size,
                              hipStream_t stream) {
    const float* x  = (const float*)d_in[0];
    const float* wg = (const float*)d_in[1];
    const float* bg = (const float*)d_in[2];
    const float* wt = (const float*)d_in[3];
    const float* bt = (const float*)d_in[4];
    const float* wp = (const float*)d_in[5];
    const float* bp = (const float*)d_in[6];
    const float* wW = (const float*)d_in[7];
    const float* bW = (const float*)d_in[8];
    ushort_t* ws = (ushort_t*)d_ws;
    float* lse = (float*)((char*)d_ws + LSE_BYTE_OFF);
    float* out = (float*)d_out;

    k_convert_w<<<512, 256, 0, stream>>>(wg, wt, wp, wW, ws);
    k_transpose_x<<<dim3(64, 4, 4), 256, 0, stream>>>(x, ws);
    k_proj_T<<<dim3(64, 4, 2), 256, 0, stream>>>(bt, bp, ws);
    k_proj_G<<<dim3(64, 4), 256, 0, stream>>>(bg, ws);
    k_attn<<<dim3(64, 4, SPLITS), 256, 0, stream>>>(ws, lse);
    k_merge<<<1024, 256, 0, stream>>>(ws, lse);
    k_out<<<dim3(64, 4, 2), 256, 0, stream>>>(x, bW, ws, out);
}

// Round 3
// 167.602 us; speedup vs baseline: 3.6835x; 3.2606x over previous
//
#include <hip/hip_runtime.h>

typedef unsigned short ushort_t;
typedef unsigned int uint_t;
typedef __attribute__((ext_vector_type(8))) short bf16x8;
typedef __attribute__((ext_vector_type(4))) float f32x4;

#define B_ 4
#define C_ 256
#define I_ 128
#define N_ 4096
#define SPLITS 4
#define KV_PER (N_ / SPLITS)
#define KVB 32
#define NIT (KV_PER / KVB)

// workspace layout in ushort (bf16) elements
#define XT_HI 0ull
#define XT_LO 4194304ull
#define W_HI  8388608ull
#define W_LO  8519680ull
#define TH_HI 8650752ull
#define TH_LO 10747904ull
#define PH_HI 12845056ull
#define PH_LO 14942208ull
#define G_BF  17039360ull      // g stored as [B][N/4][I][4] (same total size)
#define YP_OFF 0ull            // aliases XT (dead after projections)
#define YM_OFF TH_HI           // merged y aliases theta (dead after attn)
#define LSE_BYTE_OFF 38273024ull

__device__ __forceinline__ ushort_t f2bf(float f) {
    uint_t u = __float_as_uint(f);
    uint_t r = u + 0x7fffu + ((u >> 16) & 1u);   // round-to-nearest-even
    return (ushort_t)(r >> 16);
}
__device__ __forceinline__ float bf2f(ushort_t h) {
    return __uint_as_float(((uint_t)h) << 16);
}
__device__ __forceinline__ uint_t cvtpk(float lo, float hi) {
    uint_t r;
    asm volatile("v_cvt_pk_bf16_f32 %0, %1, %2" : "=v"(r) : "v"(lo), "v"(hi));
    return r;
}
__device__ __forceinline__ f32x4 mfma16(bf16x8 a, bf16x8 b, f32x4 c) {
    return __builtin_amdgcn_mfma_f32_16x16x32_bf16(a, b, c, 0, 0, 0);
}
__device__ __forceinline__ f32x4 zero4() { f32x4 z = {0.f, 0.f, 0.f, 0.f}; return z; }
__device__ __forceinline__ void gload_lds16(const void* g, void* lds) {
    __builtin_amdgcn_global_load_lds(
        (const __attribute__((address_space(1))) void*)g,
        (__attribute__((address_space(3))) void*)lds, 16, 0, 0);
}

// ---------------- kernel 1: convert all weights to bf16 hi/lo ----------------
__global__ __launch_bounds__(256) void k_convert_w(const float* wg, const float* wt,
                                                   const float* wp, const float* wW,
                                                   ushort_t* ws) {
    int idx = blockIdx.x * 256 + threadIdx.x;   // 131072 total
    float v;
    if (idx < 32768)        v = wg[idx];
    else if (idx < 65536)   v = wt[idx - 32768];
    else if (idx < 98304)   v = wp[idx - 65536];
    else                    v = wW[idx - 98304];
    ushort_t h = f2bf(v);
    ws[W_HI + idx] = h;
    ws[W_LO + idx] = f2bf(v - bf2f(h));
}

// ---------------- kernel 2: transpose+convert x -> x_t [B][N][C] hi/lo -------
__global__ __launch_bounds__(256) void k_transpose_x(const float* x, ushort_t* ws) {
    __shared__ float t[64][65];
    int b = blockIdx.z, c0 = blockIdx.y * 64, n0 = blockIdx.x * 64;
    int tid = threadIdx.x;
    int cl = tid & 63, ng = tid >> 6;
    const float* xp = x + ((size_t)(b * C_ + c0 + cl)) * N_ + n0 + ng * 16;
#pragma unroll
    for (int j = 0; j < 4; ++j) {
        float4 v = ((const float4*)xp)[j];
        t[cl][ng * 16 + j * 4 + 0] = v.x;
        t[cl][ng * 16 + j * 4 + 1] = v.y;
        t[cl][ng * 16 + j * 4 + 2] = v.z;
        t[cl][ng * 16 + j * 4 + 3] = v.w;
    }
    __syncthreads();
    int nl = tid & 63, cg = tid >> 6;
    ushort_t hh[16], ll[16];
#pragma unroll
    for (int k = 0; k < 16; ++k) {
        float v = t[cg * 16 + k][nl];
        ushort_t h = f2bf(v);
        hh[k] = h;
        ll[k] = f2bf(v - bf2f(h));
    }
    size_t dst = ((size_t)b * N_ + n0 + nl) * C_ + c0 + cg * 16;
    *(uint4*)&ws[XT_HI + dst]     = *(uint4*)&hh[0];
    *(uint4*)&ws[XT_HI + dst + 8] = *(uint4*)&hh[8];
    *(uint4*)&ws[XT_LO + dst]     = *(uint4*)&ll[0];
    *(uint4*)&ws[XT_LO + dst + 8] = *(uint4*)&ll[8];
}

// ------- kernel 3: theta/phi projections, written directly as [B][N][I] ------
__global__ __launch_bounds__(256) void k_proj_T(const float* bth, const float* bph,
                                                ushort_t* ws) {
    int b = blockIdx.y, proj = blockIdx.z;
    int w = threadIdx.x >> 6, l = threadIdx.x & 63;
    int n_base = blockIdx.x * 64 + w * 16;
    const ushort_t* wh = ws + W_HI + (size_t)(1 + proj) * 32768;
    const ushort_t* wl = ws + W_LO + (size_t)(1 + proj) * 32768;
    const ushort_t* xh = ws + XT_HI;
    const ushort_t* xl = ws + XT_LO;
    const float* bias = proj ? bph : bth;

    f32x4 acc[8];
#pragma unroll
    for (int i = 0; i < 8; ++i) acc[i] = zero4();

    int arow = n_base + (l & 15);
#pragma unroll 2
    for (int kb = 0; kb < 8; ++kb) {
        int kc = kb * 32 + 8 * (l >> 4);
        bf16x8 a_h = *(const bf16x8*)&xh[((size_t)b * N_ + arow) * C_ + kc];
        bf16x8 a_l = *(const bf16x8*)&xl[((size_t)b * N_ + arow) * C_ + kc];
#pragma unroll
        for (int i16 = 0; i16 < 8; ++i16) {
            bf16x8 b_h = *(const bf16x8*)&wh[(size_t)(i16 * 16 + (l & 15)) * C_ + kc];
            bf16x8 b_l = *(const bf16x8*)&wl[(size_t)(i16 * 16 + (l & 15)) * C_ + kc];
            acc[i16] = mfma16(a_h, b_h, acc[i16]);
            acc[i16] = mfma16(a_h, b_l, acc[i16]);
            acc[i16] = mfma16(a_l, b_h, acc[i16]);
        }
    }
    ushort_t* th = ws + (proj ? PH_HI : TH_HI);
    ushort_t* tl = ws + (proj ? PH_LO : TH_LO);
#pragma unroll
    for (int i16 = 0; i16 < 8; ++i16) {
#pragma unroll
        for (int r = 0; r < 4; ++r) {
            float v = acc[i16][r] + bias[i16 * 16 + (l & 15)];
            int n = n_base + (l >> 4) * 4 + r;
            size_t di = ((size_t)b * N_ + n) * I_ + i16 * 16 + (l & 15);
            ushort_t h = f2bf(v);
            th[di] = h;
            tl[di] = f2bf(v - bf2f(h));
        }
    }
}

// -------- kernel 4: g projection -> [B][N/4][I][4] bf16 (stage-friendly) -----
__global__ __launch_bounds__(256) void k_proj_G(const float* bg, ushort_t* ws) {
    int b = blockIdx.y, n0 = blockIdx.x * 64;
    int w = threadIdx.x >> 6, l = threadIdx.x & 63;
    int ih = (w >> 1) * 64, nh = (w & 1) * 32;
    const ushort_t* wh = ws + W_HI;
    const ushort_t* wl = ws + W_LO;
    const ushort_t* xh = ws + XT_HI;
    const ushort_t* xl = ws + XT_LO;

    f32x4 acc[4][2];
#pragma unroll
    for (int m = 0; m < 4; ++m)
#pragma unroll
        for (int n = 0; n < 2; ++n) acc[m][n] = zero4();

#pragma unroll 2
    for (int kb = 0; kb < 8; ++kb) {
        int kc = kb * 32 + 8 * (l >> 4);
        bf16x8 ah[4], al[4], bh[2], bl[2];
#pragma unroll
        for (int m = 0; m < 4; ++m) {
            ah[m] = *(const bf16x8*)&wh[(size_t)(ih + m * 16 + (l & 15)) * C_ + kc];
            al[m] = *(const bf16x8*)&wl[(size_t)(ih + m * 16 + (l & 15)) * C_ + kc];
        }
#pragma unroll
        for (int n = 0; n < 2; ++n) {
            size_t row = (size_t)b * N_ + n0 + nh + n * 16 + (l & 15);
            bh[n] = *(const bf16x8*)&xh[row * C_ + kc];
            bl[n] = *(const bf16x8*)&xl[row * C_ + kc];
        }
#pragma unroll
        for (int m = 0; m < 4; ++m)
#pragma unroll
            for (int n = 0; n < 2; ++n) {
                acc[m][n] = mfma16(ah[m], bh[n], acc[m][n]);
                acc[m][n] = mfma16(ah[m], bl[n], acc[m][n]);
                acc[m][n] = mfma16(al[m], bh[n], acc[m][n]);
            }
    }
#pragma unroll
    for (int m = 0; m < 4; ++m)
#pragma unroll
        for (int n = 0; n < 2; ++n)
#pragma unroll
            for (int r = 0; r < 4; ++r) {
                int i = ih + m * 16 + (l >> 4) * 4 + r;
                int nn = n0 + nh + n * 16 + (l & 15);
                float v = acc[m][n][r] + bg[i];
                ws[G_BF + (((size_t)b * (N_ / 4) + (nn >> 2)) * I_ + i) * 4 + (nn & 3)] = f2bf(v);
            }
}

// ---------------- kernel 5: flash attention, LDS-pipelined -------------------
// grid (32 qtiles, B, SPLITS), 512 threads = 8 waves, q-tile 128 (16 rows/wave),
// KVB=32, double-buffered LDS staging of phi hi/lo (XOR-swizzled) and g.
__global__ __launch_bounds__(512, 4) void k_attn(ushort_t* ws, float* lse) {
    __shared__ __align__(16) ushort_t smem[24576];   // 48 KB
    // phiH: smem + buf*4096 ; phiL: smem+8192 + buf*4096 ; g2: smem+16384 + buf*4096
    int b = blockIdx.y, sp = blockIdx.z;
    int w = threadIdx.x >> 6, l = threadIdx.x & 63;
    int li = l & 15, lg = l >> 4;
    int q0 = blockIdx.x * 128 + w * 16;
    const ushort_t* th = ws + TH_HI;
    const ushort_t* tl = ws + TH_LO;
    const ushort_t* ph = ws + PH_HI;
    const ushort_t* pl = ws + PH_LO;
    const ushort_t* g2g = ws + G_BF;
    ushort_t* yp = ws + YP_OFF + (size_t)sp * ((size_t)B_ * N_ * I_);

    // Q fragments (hi/lo) as B-operand
    bf16x8 qh[4], ql[4];
#pragma unroll
    for (int kb = 0; kb < 4; ++kb) {
        size_t qi = ((size_t)b * N_ + q0 + li) * I_ + kb * 32 + 8 * lg;
        qh[kb] = *(const bf16x8*)&th[qi];
        ql[kb] = *(const bf16x8*)&tl[qi];
    }

    f32x4 y[8];
#pragma unroll
    for (int dt = 0; dt < 8; ++dt) y[dt] = zero4();
    float m = -1e30f, ls = 0.f;

    int kv_beg = sp * KV_PER;
    // staging lane map (per wave, 3 gll instrs): phi rows r=w*4+(l>>4), block sb=l&15
    int s_r = w * 4 + (l >> 4);
    int s_cb = (l & 15) ^ (s_r & 7);                 // inverse swizzle on source
    size_t s_phi = ((size_t)b * N_ + s_r) * I_ + s_cb * 8;     // + kv0*I_ later
    size_t s_g   = (((size_t)b * (N_ / 4) + w) * I_) * 4 + l * 8;  // + (kv0>>2)*512 later

    // prologue: stage tile 0 into buf 0
    {
        size_t pofs = s_phi + (size_t)kv_beg * I_;
        gload_lds16(ph + pofs, smem + w * 512);
        gload_lds16(pl + pofs, smem + 8192 + w * 512);
        gload_lds16(g2g + s_g + ((size_t)(kv_beg >> 2)) * 512, smem + 16384 + w * 512);
    }
    __syncthreads();

    for (int it = 0; it < NIT; ++it) {
        int buf = it & 1;
        // stage next tile into the other buffer
        if (it + 1 < NIT) {
            int kvn = kv_beg + (it + 1) * KVB;
            int nb = buf ^ 1;
            size_t pofs = s_phi + (size_t)kvn * I_;
            gload_lds16(ph + pofs, smem + nb * 4096 + w * 512);
            gload_lds16(pl + pofs, smem + 8192 + nb * 4096 + w * 512);
            gload_lds16(g2g + s_g + ((size_t)(kvn >> 2)) * 512, smem + 16384 + nb * 4096 + w * 512);
        }
        const ushort_t* bufPH = smem + buf * 4096;
        const ushort_t* bufPL = smem + 8192 + buf * 4096;
        const ushort_t* bufG  = smem + 16384 + buf * 4096;

        // ---- QK^T: A = phi rows (kv) from LDS (swizzled), B = theta (regs) ----
        f32x4 f0 = zero4(), f1 = zero4();
#pragma unroll
        for (int kb = 0; kb < 4; ++kb) {
            int sb = ((kb * 4 + lg) ^ (li & 7)) * 8;
            bf16x8 a0h = *(const bf16x8*)&bufPH[li * 128 + sb];
            bf16x8 a0l = *(const bf16x8*)&bufPL[li * 128 + sb];
            bf16x8 a1h = *(const bf16x8*)&bufPH[(16 + li) * 128 + sb];
            bf16x8 a1l = *(const bf16x8*)&bufPL[(16 + li) * 128 + sb];
            f0 = mfma16(a0h, qh[kb], f0);
            f0 = mfma16(a0h, ql[kb], f0);
            f0 = mfma16(a0l, qh[kb], f0);
            f1 = mfma16(a1h, qh[kb], f1);
            f1 = mfma16(a1h, ql[kb], f1);
            f1 = mfma16(a1l, qh[kb], f1);
        }
        // ---- online softmax (lane-local row, 2 shuffles per reduce) ----
        float tm = fmaxf(fmaxf(fmaxf(f0[0], f0[1]), fmaxf(f0[2], f0[3])),
                         fmaxf(fmaxf(f1[0], f1[1]), fmaxf(f1[2], f1[3])));
        tm = fmaxf(tm, __shfl_xor(tm, 16));
        tm = fmaxf(tm, __shfl_xor(tm, 32));
        if (__ballot(tm > m + 8.f)) {
            float mn = fmaxf(m, tm);
            float sc = __expf(m - mn);
            ls *= sc; m = mn;
            float s0 = __shfl(sc, 4 * lg + 0);
            float s1 = __shfl(sc, 4 * lg + 1);
            float s2 = __shfl(sc, 4 * lg + 2);
            float s3 = __shfl(sc, 4 * lg + 3);
#pragma unroll
            for (int dt = 0; dt < 8; ++dt) {
                y[dt][0] *= s0; y[dt][1] *= s1; y[dt][2] *= s2; y[dt][3] *= s3;
            }
        }
        float p00 = __expf(f0[0] - m), p01 = __expf(f0[1] - m);
        float p02 = __expf(f0[2] - m), p03 = __expf(f0[3] - m);
        float p10 = __expf(f1[0] - m), p11 = __expf(f1[1] - m);
        float p12 = __expf(f1[2] - m), p13 = __expf(f1[3] - m);
        float rs = ((p00 + p01) + (p02 + p03)) + ((p10 + p11) + (p12 + p13));
        rs += __shfl_xor(rs, 16);
        rs += __shfl_xor(rs, 32);
        ls += rs;
        // pack P: a[j] = P[q=li][kv: j<4 -> 4lg+j ; j>=4 -> 16+4lg+(j-4)]
        union { uint_t u[4]; bf16x8 v; } pu;
        pu.u[0] = cvtpk(p00, p01);
        pu.u[1] = cvtpk(p02, p03);
        pu.u[2] = cvtpk(p10, p11);
        pu.u[3] = cvtpk(p12, p13);
        // ---- PV: B = g fragments from LDS, same k-slot map ----
#pragma unroll
        for (int dt = 0; dt < 8; ++dt) {
            int i = dt * 16 + li;
            uint2 ga = *(const uint2*)&bufG[(lg * 128 + i) * 4];
            uint2 gb = *(const uint2*)&bufG[((4 + lg) * 128 + i) * 4];
            union { uint_t u[4]; bf16x8 v; } gu;
            gu.u[0] = ga.x; gu.u[1] = ga.y; gu.u[2] = gb.x; gu.u[3] = gb.y;
            y[dt] = mfma16(pu.v, gu.v, y[dt]);
        }
        __syncthreads();   // drains gll (vmcnt) + ds reads (lgkmcnt), flips buffer
    }

    // epilogue: normalized partial + lse
    float inv = 1.0f / ls;
    float i0 = __shfl(inv, 4 * lg + 0);
    float i1 = __shfl(inv, 4 * lg + 1);
    float i2 = __shfl(inv, 4 * lg + 2);
    float i3 = __shfl(inv, 4 * lg + 3);
#pragma unroll
    for (int dt = 0; dt < 8; ++dt) {
        size_t base = ((size_t)b * N_ + q0 + 4 * lg) * I_ + dt * 16 + li;
        yp[base]            = f2bf(y[dt][0] * i0);
        yp[base + I_]       = f2bf(y[dt][1] * i1);
        yp[base + 2 * I_]   = f2bf(y[dt][2] * i2);
        yp[base + 3 * I_]   = f2bf(y[dt][3] * i3);
    }
    if (l < 16)
        lse[((size_t)sp * B_ + b) * N_ + q0 + l] = m + __logf(ls);
}

// ---------------- kernel 5b: merge split-KV partials -------------------------
__global__ __launch_bounds__(256) void k_merge(ushort_t* ws, const float* lse) {
    int t = blockIdx.x * 256 + threadIdx.x;     // 1024 blocks -> B*N*I/8 threads
    size_t base = (size_t)t * 8;
    size_t row = base >> 7;                     // / I_
    float l0 = lse[row];
    float l1 = lse[(size_t)B_ * N_ + row];
    float l2 = lse[2 * (size_t)B_ * N_ + row];
    float l3 = lse[3 * (size_t)B_ * N_ + row];
    float mx = fmaxf(fmaxf(l0, l1), fmaxf(l2, l3));
    float w0 = __expf(l0 - mx), w1 = __expf(l1 - mx);
    float w2 = __expf(l2 - mx), w3 = __expf(l3 - mx);
    float inv = 1.0f / (w0 + w1 + w2 + w3);
    w0 *= inv; w1 *= inv; w2 *= inv; w3 *= inv;
    const ushort_t* yp = ws + YP_OFF;
    const size_t STRIDE = (size_t)B_ * N_ * I_;
    float acc[8];
#pragma unroll
    for (int j = 0; j < 8; ++j) acc[j] = 0.f;
    float wgt[4] = {w0, w1, w2, w3};
#pragma unroll
    for (int sp = 0; sp < 4; ++sp) {
        bf16x8 v = *(const bf16x8*)&yp[sp * STRIDE + base];
#pragma unroll
        for (int j = 0; j < 8; ++j) acc[j] += wgt[sp] * bf2f((ushort_t)v[j]);
    }
    ushort_t o[8];
#pragma unroll
    for (int j = 0; j < 8; ++j) o[j] = f2bf(acc[j]);
    *(uint4*)&ws[YM_OFF + base] = *(uint4*)&o[0];
}

// ---------------- kernel 6: output projection + residual ---------------------
__global__ __launch_bounds__(256) void k_out(const float* x, const float* bW,
                                             const ushort_t* ws, float* out) {
    int b = blockIdx.y, n0 = blockIdx.x * 64;
    int w = threadIdx.x >> 6, l = threadIdx.x & 63;
    int cw = blockIdx.z * 128 + (w >> 1) * 64;
    int nh = (w & 1) * 32;
    const ushort_t* wh = ws + W_HI + 98304;   // w_W [256][128]
    const ushort_t* wl = ws + W_LO + 98304;
    const ushort_t* yb = ws + YM_OFF;

    f32x4 acc[4][2];
#pragma unroll
    for (int m = 0; m < 4; ++m)
#pragma unroll
        for (int n = 0; n < 2; ++n) acc[m][n] = zero4();

#pragma unroll 2
    for (int kb = 0; kb < 4; ++kb) {
        int kc = kb * 32 + 8 * (l >> 4);
        bf16x8 ah[4], al[4], by[2];
#pragma unroll
        for (int m = 0; m < 4; ++m) {
            ah[m] = *(const bf16x8*)&wh[(size_t)(cw + m * 16 + (l & 15)) * I_ + kc];
            al[m] = *(const bf16x8*)&wl[(size_t)(cw + m * 16 + (l & 15)) * I_ + kc];
        }
#pragma unroll
        for (int n = 0; n < 2; ++n)
            by[n] = *(const bf16x8*)&yb[((size_t)b * N_ + n0 + nh + n * 16 + (l & 15)) * I_ + kc];
#pragma unroll
        for (int m = 0; m < 4; ++m)
#pragma unroll
            for (int n = 0; n < 2; ++n) {
                acc[m][n] = mfma16(ah[m], by[n], acc[m][n]);
                acc[m][n] = mfma16(al[m], by[n], acc[m][n]);
            }
    }
#pragma unroll
    for (int m = 0; m < 4; ++m)
#pragma unroll
        for (int n = 0; n < 2; ++n)
#pragma unroll
            for (int r = 0; r < 4; ++r) {
                int c = cw + m * 16 + (l >> 4) * 4 + r;
                int nn = n0 + nh + n * 16 + (l & 15);
                size_t xi = ((size_t)b * C_ + c) * N_ + nn;
                out[xi] = acc[m][n][r] + bW[c] + x[xi];
            }
}

extern "C" void kernel_launch(void* const* d_in, const int* in_sizes, int n_in,
                              void* d_out, int out_size, void* d_ws, size_t ws_size,
                              hipStream_t stream) {
    const float* x  = (const float*)d_in[0];
    const float* wg = (const float*)d_in[1];
    const float* bg = (const float*)d_in[2];
    const float* wt = (const float*)d_in[3];
    const float* bt = (const float*)d_in[4];
    const float* wp = (const float*)d_in[5];
    const float* bp = (const float*)d_in[6];
    const float* wW = (const float*)d_in[7];
    const float* bW = (const float*)d_in[8];
    ushort_t* ws = (ushort_t*)d_ws;
    float* lse = (float*)((char*)d_ws + LSE_BYTE_OFF);
    float* out = (float*)d_out;

    k_convert_w<<<512, 256, 0, stream>>>(wg, wt, wp, wW, ws);
    k_transpose_x<<<dim3(64, 4, 4), 256, 0, stream>>>(x, ws);
    k_proj_T<<<dim3(64, 4, 2), 256, 0, stream>>>(bt, bp, ws);
    k_proj_G<<<dim3(64, 4), 256, 0, stream>>>(bg, ws);
    k_attn<<<dim3(32, 4, SPLITS), 512, 0, stream>>>(ws, lse);
    k_merge<<<1024, 256, 0, stream>>>(ws, lse);
    k_out<<<dim3(64, 4, 2), 256, 0, stream>>>(x, bW, ws, out);
}

// Round 5
// 119.626 us; speedup vs baseline: 5.1607x; 1.4010x over previous
//
#include <hip/hip_runtime.h>

typedef unsigned short ushort_t;
typedef unsigned int uint_t;
typedef _Float16 f16;
typedef __attribute__((ext_vector_type(8))) _Float16 f16x8;
typedef __attribute__((ext_vector_type(2))) _Float16 f16x2;
typedef __attribute__((ext_vector_type(4))) float f32x4;

#define B_ 4
#define C_ 256
#define I_ 128
#define N_ 4096
#define SPLITS 4
#define KV_PER (N_ / SPLITS)
#define KVB 64
#define NIT (KV_PER / KVB)

// ws layout in 2-byte units
#define XT_HI 0ull            // f16 hi of x_t [B][N][C] (4M)
#define XT_LO 4194304ull      // f16 lo (4M)
#define W_F   8388608ull      // f16 weights: wg@0 wt@32768 wp@65536 wW@98304 (131072)
#define TH_F  8519680ull      // f16 theta [B][N][I] (2M)
#define PH_F  10616832ull     // f16 phi   [B][N][I] (2M)
#define G2_F  12713984ull     // f16 g     [B][N/4][I][4] (2M)
#define YP_OFF 0ull           // partials [S][B][N][I] f16 (8M), aliases XT (dead)
#define YM_OFF TH_F           // merged y f16, aliases theta (dead after attn)
#define LSE_BYTE_OFF 29622272ull   // floats [S][B][N]

__device__ __forceinline__ f16x2 pkrtz(float a, float b) {
    auto r = __builtin_amdgcn_cvt_pkrtz(a, b);   // __fp16 ext_vector(2)
    f16x2 o;
    __builtin_memcpy(&o, &r, sizeof(o));
    return o;
}
__device__ __forceinline__ f32x4 mfma16h(f16x8 a, f16x8 b, f32x4 c) {
    return __builtin_amdgcn_mfma_f32_16x16x32_f16(a, b, c, 0, 0, 0);
}
__device__ __forceinline__ f32x4 zero4() { f32x4 z = {0.f, 0.f, 0.f, 0.f}; return z; }
__device__ __forceinline__ void gload_lds16(const void* g, void* lds) {
    __builtin_amdgcn_global_load_lds(
        (const __attribute__((address_space(1))) void*)g,
        (__attribute__((address_space(3))) void*)lds, 16, 0, 0);
}

// ---------------- kernel 1: convert all weights to f16 -----------------------
__global__ __launch_bounds__(256) void k_convert_w(const float* wg, const float* wt,
                                                   const float* wp, const float* wW,
                                                   ushort_t* ws) {
    int idx = blockIdx.x * 256 + threadIdx.x;   // 131072 total
    float v;
    if (idx < 32768)        v = wg[idx];
    else if (idx < 65536)   v = wt[idx - 32768];
    else if (idx < 98304)   v = wp[idx - 65536];
    else                    v = wW[idx - 98304];
    ((f16*)(ws + W_F))[idx] = (f16)v;
}

// ---------------- kernel 2: transpose+convert x -> x_t [B][N][C] f16 hi/lo ---
__global__ __launch_bounds__(256) void k_transpose_x(const float* x, ushort_t* ws) {
    __shared__ float t[64][65];
    int b = blockIdx.z, c0 = blockIdx.y * 64, n0 = blockIdx.x * 64;
    int tid = threadIdx.x;
    int cl = tid & 63, ng = tid >> 6;
    const float* xp = x + ((size_t)(b * C_ + c0 + cl)) * N_ + n0 + ng * 16;
#pragma unroll
    for (int j = 0; j < 4; ++j) {
        float4 v = ((const float4*)xp)[j];
        t[cl][ng * 16 + j * 4 + 0] = v.x;
        t[cl][ng * 16 + j * 4 + 1] = v.y;
        t[cl][ng * 16 + j * 4 + 2] = v.z;
        t[cl][ng * 16 + j * 4 + 3] = v.w;
    }
    __syncthreads();
    int nl = tid & 63, cg = tid >> 6;
    f16 hv[16], lv[16];
#pragma unroll
    for (int k = 0; k < 16; ++k) {
        float v = t[cg * 16 + k][nl];
        f16 h = (f16)v;
        hv[k] = h;
        lv[k] = (f16)(v - (float)h);
    }
    size_t dst = ((size_t)b * N_ + n0 + nl) * C_ + c0 + cg * 16;
    *(uint4*)&ws[XT_HI + dst]     = *(uint4*)&hv[0];
    *(uint4*)&ws[XT_HI + dst + 8] = *(uint4*)&hv[8];
    *(uint4*)&ws[XT_LO + dst]     = *(uint4*)&lv[0];
    *(uint4*)&ws[XT_LO + dst + 8] = *(uint4*)&lv[8];
}

// -------- kernel 3: fused theta/phi/g projections (x_t read once) ------------
// 512 thr: wave w: n-sub (w&3)*16, i16-half (w>>2). A = x_t rows (f16 hi/lo),
// B = f16 weights (single). out = x W^T + bias.
__global__ __launch_bounds__(512) void k_proj_all(const float* bg, const float* bth,
                                                  const float* bph, ushort_t* ws) {
    int b = blockIdx.y, n0 = blockIdx.x * 64;
    int w = threadIdx.x >> 6, l = threadIdx.x & 63;
    int li = l & 15, lg = l >> 4;
    int wn = (w & 3) * 16;
    int ihb = (w >> 2) * 4;
    const f16* xh = (const f16*)(ws + XT_HI);
    const f16* xl = (const f16*)(ws + XT_LO);
    const f16* wf = (const f16*)(ws + W_F);

    f32x4 acc[3][4];
#pragma unroll
    for (int p = 0; p < 3; ++p)
#pragma unroll
        for (int t = 0; t < 4; ++t) acc[p][t] = zero4();

    size_t arow = ((size_t)b * N_ + n0 + wn + li) * C_;
#pragma unroll 2
    for (int kb = 0; kb < 8; ++kb) {
        int kc = kb * 32 + 8 * lg;
        f16x8 ah = *(const f16x8*)&xh[arow + kc];
        f16x8 al = *(const f16x8*)&xl[arow + kc];
#pragma unroll
        for (int p = 0; p < 3; ++p)
#pragma unroll
            for (int t = 0; t < 4; ++t) {
                f16x8 bw = *(const f16x8*)&wf[(size_t)p * 32768 + (size_t)((ihb + t) * 16 + li) * C_ + kc];
                acc[p][t] = mfma16h(ah, bw, acc[p][t]);
                acc[p][t] = mfma16h(al, bw, acc[p][t]);
            }
    }
    f16* g2p = (f16*)(ws + G2_F);
    f16* thp = (f16*)(ws + TH_F);
    f16* php = (f16*)(ws + PH_F);
#pragma unroll
    for (int p = 0; p < 3; ++p) {
        const float* bias = (p == 0) ? bg : (p == 1) ? bth : bph;
#pragma unroll
        for (int t = 0; t < 4; ++t) {
            int i = (ihb + t) * 16 + li;
            float bs = bias[i];
#pragma unroll
            for (int r = 0; r < 4; ++r) {
                int n = n0 + wn + 4 * lg + r;
                float v = acc[p][t][r] + bs;
                if (p == 0)
                    g2p[(((size_t)b * (N_ / 4) + (n >> 2)) * I_ + i) * 4 + (n & 3)] = (f16)v;
                else if (p == 1)
                    thp[((size_t)b * N_ + n) * I_ + i] = (f16)v;
                else
                    php[((size_t)b * N_ + n) * I_ + i] = (f16)v;
            }
        }
    }
}

// ---------------- kernel 4: flash attention, f16, KVB=64 ---------------------
// grid (32 qtiles, B, SPLITS), 512 thr = 8 waves, 16 q-rows/wave.
// Swapped QK^T (A=phi rows from swizzled LDS, B=theta regs) -> P lane-local.
// PV in-register via consistent custom k-slot map on P (A) and g (B).
__global__ __launch_bounds__(512, 4) void k_attn(ushort_t* ws, float* lse) {
    __shared__ __align__(16) ushort_t smem[32768];   // 64KB: phi@0/8192, g@16384/24576
    int b = blockIdx.y, sp = blockIdx.z;
    int w = threadIdx.x >> 6, l = threadIdx.x & 63;
    int li = l & 15, lg = l >> 4;
    int q0 = blockIdx.x * 128 + w * 16;
    const f16* th = (const f16*)(ws + TH_F);
    const f16* ph = (const f16*)(ws + PH_F);
    const f16* g2 = (const f16*)(ws + G2_F);
    f16* yp = (f16*)(ws + YP_OFF) + (size_t)sp * ((size_t)B_ * N_ * I_);

    f16x8 qf[4];
#pragma unroll
    for (int kb = 0; kb < 4; ++kb)
        qf[kb] = *(const f16x8*)&th[((size_t)b * N_ + q0 + li) * I_ + kb * 32 + 8 * lg];

    f32x4 y[8];
#pragma unroll
    for (int dt = 0; dt < 8; ++dt) y[dt] = zero4();
    float m = -1e30f, ls = 0.f;

    int kv_beg = sp * KV_PER;
    // staging: phi rows w*8+{0..7} (2 gll), g quads w*2+{0,1} (2 gll)
    int srow = l >> 4;
    size_t sp0 = ((size_t)b * N_ + w * 8 + srow) * I_ + ((l & 15) ^ srow) * 8;
    size_t sp1 = ((size_t)b * N_ + w * 8 + 4 + srow) * I_ + (((l & 15) ^ srow) ^ 4) * 8;
    size_t sg0 = ((size_t)b * (N_ / 4) + w * 2) * (I_ * 4) + l * 8;
    int dp = w * 1024;            // phi dest base (2B units)
    int dg = 16384 + w * 1024;    // g dest base

    auto stage = [&](int kv0, int bufsel) {
        int bo = bufsel ? 8192 : 0;
        gload_lds16(ph + sp0 + (size_t)kv0 * I_, smem + bo + dp);
        gload_lds16(ph + sp1 + (size_t)kv0 * I_, smem + bo + dp + 512);
        gload_lds16(g2 + sg0 + (size_t)kv0 * 128, smem + bo + dg);
        gload_lds16(g2 + sg0 + (size_t)kv0 * 128 + 512, smem + bo + dg + 512);
    };

    stage(kv_beg, 0);
    __syncthreads();

    for (int it = 0; it < NIT; ++it) {
        int buf = it & 1;
        if (it + 1 < NIT) stage(kv_beg + (it + 1) * KVB, buf ^ 1);
        const f16* pbuf = (const f16*)(smem + (buf ? 8192 : 0));
        const f16* gbuf = (const f16*)(smem + 16384 + (buf ? 8192 : 0));

        // ---- QK^T: f[h][r] = logit for kv = h*16 + 4*lg + r, q = li ----
        f32x4 f[4];
#pragma unroll
        for (int h = 0; h < 4; ++h) f[h] = zero4();
        __builtin_amdgcn_s_setprio(1);
#pragma unroll
        for (int kb = 0; kb < 4; ++kb) {
            int cc = ((kb * 4 + lg) ^ (li & 7)) * 8;
#pragma unroll
            for (int h = 0; h < 4; ++h) {
                f16x8 a = *(const f16x8*)&pbuf[(h * 16 + li) * 128 + cc];
                f[h] = mfma16h(a, qf[kb], f[h]);
            }
        }
        __builtin_amdgcn_s_setprio(0);

        // ---- online softmax ----
        float tm = fmaxf(fmaxf(fmaxf(f[0][0], f[0][1]), fmaxf(f[0][2], f[0][3])),
                         fmaxf(fmaxf(f[1][0], f[1][1]), fmaxf(f[1][2], f[1][3])));
        tm = fmaxf(tm, fmaxf(fmaxf(fmaxf(f[2][0], f[2][1]), fmaxf(f[2][2], f[2][3])),
                             fmaxf(fmaxf(f[3][0], f[3][1]), fmaxf(f[3][2], f[3][3]))));
        tm = fmaxf(tm, __shfl_xor(tm, 16));
        tm = fmaxf(tm, __shfl_xor(tm, 32));
        if (__ballot(tm > m + 8.f)) {          // defer-max (T13)
            float mn = fmaxf(m, tm);
            float sc = __expf(m - mn);
            ls *= sc; m = mn;
            float s0 = __shfl(sc, 4 * lg + 0);
            float s1 = __shfl(sc, 4 * lg + 1);
            float s2 = __shfl(sc, 4 * lg + 2);
            float s3 = __shfl(sc, 4 * lg + 3);
#pragma unroll
            for (int dt = 0; dt < 8; ++dt) {
                y[dt][0] *= s0; y[dt][1] *= s1; y[dt][2] *= s2; y[dt][3] *= s3;
            }
        }
        float rs = 0.f;
#pragma unroll
        for (int h = 0; h < 4; ++h)
#pragma unroll
            for (int r = 0; r < 4; ++r) {
                f[h][r] = __expf(f[h][r] - m);
                rs += f[h][r];
            }
        rs += __shfl_xor(rs, 16);
        rs += __shfl_xor(rs, 32);
        ls += rs;

        // pack P: chunk0 a[j]: j<4 -> kv 4lg+j (f0), j>=4 -> 16+4lg+(j-4) (f1)
        union PU { f16x2 h2[4]; f16x8 v; };
        PU pA, pB;
        pA.h2[0] = pkrtz(f[0][0], f[0][1]); pA.h2[1] = pkrtz(f[0][2], f[0][3]);
        pA.h2[2] = pkrtz(f[1][0], f[1][1]); pA.h2[3] = pkrtz(f[1][2], f[1][3]);
        pB.h2[0] = pkrtz(f[2][0], f[2][1]); pB.h2[1] = pkrtz(f[2][2], f[2][3]);
        pB.h2[2] = pkrtz(f[3][0], f[3][1]); pB.h2[3] = pkrtz(f[3][2], f[3][3]);

        // ---- PV: B = g frags from LDS with the same k-slot map ----
        __builtin_amdgcn_s_setprio(1);
#pragma unroll
        for (int dt = 0; dt < 8; ++dt) {
            int i4 = (dt * 16 + li) * 4;
            union GU { uint_t u[4]; f16x8 v; };
            GU g0, g1;
            *(uint2*)&g0.u[0] = *(const uint2*)&gbuf[lg * 512 + i4];
            *(uint2*)&g0.u[2] = *(const uint2*)&gbuf[(4 + lg) * 512 + i4];
            y[dt] = mfma16h(pA.v, g0.v, y[dt]);
            *(uint2*)&g1.u[0] = *(const uint2*)&gbuf[(8 + lg) * 512 + i4];
            *(uint2*)&g1.u[2] = *(const uint2*)&gbuf[(12 + lg) * 512 + i4];
            y[dt] = mfma16h(pB.v, g1.v, y[dt]);
        }
        __builtin_amdgcn_s_setprio(0);
        __syncthreads();
    }

    // epilogue: normalized partial + lse
    float inv = 1.0f / ls;
    float i0 = __shfl(inv, 4 * lg + 0);
    float i1 = __shfl(inv, 4 * lg + 1);
    float i2 = __shfl(inv, 4 * lg + 2);
    float i3 = __shfl(inv, 4 * lg + 3);
#pragma unroll
    for (int dt = 0; dt < 8; ++dt) {
        size_t base = ((size_t)b * N_ + q0 + 4 * lg) * I_ + dt * 16 + li;
        yp[base]          = (f16)(y[dt][0] * i0);
        yp[base + I_]     = (f16)(y[dt][1] * i1);
        yp[base + 2 * I_] = (f16)(y[dt][2] * i2);
        yp[base + 3 * I_] = (f16)(y[dt][3] * i3);
    }
    if (l < 16)
        lse[((size_t)sp * B_ + b) * N_ + q0 + l] = m + __logf(ls);
}

// ---------------- kernel 5: merge split-KV partials --------------------------
__global__ __launch_bounds__(256) void k_merge(ushort_t* ws, const float* lse) {
    int t = blockIdx.x * 256 + threadIdx.x;     // B*N*I/8 threads
    size_t base = (size_t)t * 8;
    size_t row = base >> 7;
    float l0 = lse[row];
    float l1 = lse[(size_t)B_ * N_ + row];
    float l2 = lse[2 * (size_t)B_ * N_ + row];
    float l3 = lse[3 * (size_t)B_ * N_ + row];
    float mx = fmaxf(fmaxf(l0, l1), fmaxf(l2, l3));
    float w0 = __expf(l0 - mx), w1 = __expf(l1 - mx);
    float w2 = __expf(l2 - mx), w3 = __expf(l3 - mx);
    float inv = 1.0f / (w0 + w1 + w2 + w3);
    float wgt[4] = {w0 * inv, w1 * inv, w2 * inv, w3 * inv};
    const f16* yp = (const f16*)(ws + YP_OFF);
    const size_t STRIDE = (size_t)B_ * N_ * I_;
    float acc[8];
#pragma unroll
    for (int j = 0; j < 8; ++j) acc[j] = 0.f;
#pragma unroll
    for (int sp = 0; sp < 4; ++sp) {
        f16x8 v = *(const f16x8*)&yp[sp * STRIDE + base];
#pragma unroll
        for (int j = 0; j < 8; ++j) acc[j] += wgt[sp] * (float)v[j];
    }
    f16 o[8];
#pragma unroll
    for (int j = 0; j < 8; ++j) o[j] = (f16)acc[j];
    *(uint4*)&((f16*)(ws + YM_OFF))[base] = *(uint4*)&o[0];
}

// ---------------- kernel 6: output projection + residual ---------------------
__global__ __launch_bounds__(256) void k_out(const float* x, const float* bW,
                                             const ushort_t* ws, float* out) {
    int b = blockIdx.y, n0 = blockIdx.x * 64;
    int w = threadIdx.x >> 6, l = threadIdx.x & 63;
    int li = l & 15, lg = l >> 4;
    int cw = blockIdx.z * 128 + (w >> 1) * 64;
    int nh = (w & 1) * 32;
    const f16* wfp = (const f16*)(ws + W_F) + 98304;   // w_W [256][128] f16
    const f16* yb  = (const f16*)(ws + YM_OFF);

    f32x4 acc[4][2];
#pragma unroll
    for (int mm = 0; mm < 4; ++mm)
#pragma unroll
        for (int n = 0; n < 2; ++n) acc[mm][n] = zero4();

#pragma unroll 2
    for (int kb = 0; kb < 4; ++kb) {
        int kc = kb * 32 + 8 * lg;
        f16x8 a[4], byv[2];
#pragma unroll
        for (int mm = 0; mm < 4; ++mm)
            a[mm] = *(const f16x8*)&wfp[(size_t)(cw + mm * 16 + li) * I_ + kc];
#pragma unroll
        for (int n = 0; n < 2; ++n)
            byv[n] = *(const f16x8*)&yb[((size_t)b * N_ + n0 + nh + n * 16 + li) * I_ + kc];
#pragma unroll
        for (int mm = 0; mm < 4; ++mm)
#pragma unroll
            for (int n = 0; n < 2; ++n)
                acc[mm][n] = mfma16h(a[mm], byv[n], acc[mm][n]);
    }
#pragma unroll
    for (int mm = 0; mm < 4; ++mm)
#pragma unroll
        for (int n = 0; n < 2; ++n)
#pragma unroll
            for (int r = 0; r < 4; ++r) {
                int c = cw + mm * 16 + lg * 4 + r;
                int nn = n0 + nh + n * 16 + li;
                size_t xi = ((size_t)b * C_ + c) * N_ + nn;
                out[xi] = acc[mm][n][r] + bW[c] + x[xi];
            }
}

extern "C" void kernel_launch(void* const* d_in, const int* in_sizes, int n_in,
                              void* d_out, int out_size, void* d_ws, size_t ws_size,
                              hipStream_t stream) {
    const float* x  = (const float*)d_in[0];
    const float* wg = (const float*)d_in[1];
    const float* bg = (const float*)d_in[2];
    const float* wt = (const float*)d_in[3];
    const float* bt = (const float*)d_in[4];
    const float* wp = (const float*)d_in[5];
    const float* bp = (const float*)d_in[6];
    const float* wW = (const float*)d_in[7];
    const float* bW = (const float*)d_in[8];
    ushort_t* ws = (ushort_t*)d_ws;
    float* lse = (float*)((char*)d_ws + LSE_BYTE_OFF);
    float* out = (float*)d_out;

    k_convert_w<<<512, 256, 0, stream>>>(wg, wt, wp, wW, ws);
    k_transpose_x<<<dim3(64, 4, 4), 256, 0, stream>>>(x, ws);
    k_proj_all<<<dim3(64, 4), 512, 0, stream>>>(bg, bt, bp, ws);
    k_attn<<<dim3(32, 4, SPLITS), 512, 0, stream>>>(ws, lse);
    k_merge<<<1024, 256, 0, stream>>>(ws, lse);
    k_out<<<dim3(64, 4, 2), 256, 0, stream>>>(x, bW, ws, out);
}

// Round 7
// 117.852 us; speedup vs baseline: 5.2384x; 1.0151x over previous
//
#include <hip/hip_runtime.h>

typedef unsigned short ushort_t;
typedef unsigned int uint_t;
typedef _Float16 f16;
typedef __attribute__((ext_vector_type(8))) _Float16 f16x8;
typedef __attribute__((ext_vector_type(2))) _Float16 f16x2;
typedef __attribute__((ext_vector_type(4))) float f32x4;

#define B_ 4
#define C_ 256
#define I_ 128
#define N_ 4096
#define KVB 32
#define LOG2E 1.44269504f

// ws layout in 2-byte units
#define XT_F 0ull             // f16 x_t [B][N][C] (4,194,304)
#define W_F  4194304ull       // f16 weights: wg@0 wt@32768 wp@65536 wW@98304
#define TH_F 4325376ull       // f16 theta (pre-scaled by log2e) [B][N][I]
#define PH_F 6422528ull       // f16 phi [B][N][I]
#define G2_F 8519680ull       // f16 g [B][N/4][I][4]
#define YP_F 10616832ull      // f16 partials [S][B][N][I], S = 4 or 8
// lse (f32, base-2) at byte offset 2*(YP_F + S*2097152)

__device__ __forceinline__ float exp2_hw(float x) { return __builtin_amdgcn_exp2f(x); }
__device__ __forceinline__ float log2_hw(float x) { return __builtin_amdgcn_logf(x); }

__device__ __forceinline__ f16x2 pkrtz(float a, float b) {
    auto r = __builtin_amdgcn_cvt_pkrtz(a, b);
    f16x2 o;
    __builtin_memcpy(&o, &r, sizeof(o));
    return o;
}
__device__ __forceinline__ f32x4 mfma16h(f16x8 a, f16x8 b, f32x4 c) {
    return __builtin_amdgcn_mfma_f32_16x16x32_f16(a, b, c, 0, 0, 0);
}
__device__ __forceinline__ f32x4 zero4() { f32x4 z = {0.f, 0.f, 0.f, 0.f}; return z; }
__device__ __forceinline__ void gload_lds16(const void* g, void* lds) {
    __builtin_amdgcn_global_load_lds(
        (const __attribute__((address_space(1))) void*)g,
        (__attribute__((address_space(3))) void*)lds, 16, 0, 0);
}

// ------- kernel 1: transpose+convert x -> x_t f16; fused weight convert ------
__global__ __launch_bounds__(256) void k_transpose_x(const float* x, const float* wg,
        const float* wt, const float* wp, const float* wW, ushort_t* ws) {
    if (blockIdx.x >= 64) {
        // weight conversion: 32 "blocks" x 256 thr x 16 elems = 131072
        int idx = (((blockIdx.x - 64) * 16 + blockIdx.y * 4 + blockIdx.z) * 256
                   + threadIdx.x) * 16;
        const float* src;
        int off;
        if (idx < 32768)      { src = wg; off = idx; }
        else if (idx < 65536) { src = wt; off = idx - 32768; }
        else if (idx < 98304) { src = wp; off = idx - 65536; }
        else                  { src = wW; off = idx - 98304; }
        f16 o[16];
#pragma unroll
        for (int j = 0; j < 16; ++j) o[j] = (f16)src[off + j];
        f16* wd = (f16*)(ws + W_F);
        *(uint4*)&wd[idx]     = *(uint4*)&o[0];
        *(uint4*)&wd[idx + 8] = *(uint4*)&o[8];
        return;
    }
    __shared__ float t[64][65];
    int b = blockIdx.z, c0 = blockIdx.y * 64, n0 = blockIdx.x * 64;
    int tid = threadIdx.x;
    int cl = tid & 63, ng = tid >> 6;
    const float* xp = x + ((size_t)(b * C_ + c0 + cl)) * N_ + n0 + ng * 16;
#pragma unroll
    for (int j = 0; j < 4; ++j) {
        float4 v = ((const float4*)xp)[j];
        t[cl][ng * 16 + j * 4 + 0] = v.x;
        t[cl][ng * 16 + j * 4 + 1] = v.y;
        t[cl][ng * 16 + j * 4 + 2] = v.z;
        t[cl][ng * 16 + j * 4 + 3] = v.w;
    }
    __syncthreads();
    int nl = tid & 63, cg = tid >> 6;
    f16 hv[16];
#pragma unroll
    for (int k = 0; k < 16; ++k) hv[k] = (f16)t[cg * 16 + k][nl];
    size_t dst = ((size_t)b * N_ + n0 + nl) * C_ + c0 + cg * 16;
    f16* xd = (f16*)(ws + XT_F);
    *(uint4*)&xd[dst]     = *(uint4*)&hv[0];
    *(uint4*)&xd[dst + 8] = *(uint4*)&hv[8];
}

// -------- kernel 2: fused theta/phi/g projections (single-f16 x) -------------
__global__ __launch_bounds__(512) void k_proj_all(const float* bg, const float* bth,
                                                  const float* bph, ushort_t* ws) {
    int b = blockIdx.y, n0 = blockIdx.x * 64;
    int w = threadIdx.x >> 6, l = threadIdx.x & 63;
    int li = l & 15, lg = l >> 4;
    int wn = (w & 3) * 16;
    int ihb = (w >> 2) * 4;
    const f16* xh = (const f16*)(ws + XT_F);
    const f16* wf = (const f16*)(ws + W_F);

    f32x4 acc[3][4];
#pragma unroll
    for (int p = 0; p < 3; ++p)
#pragma unroll
        for (int t = 0; t < 4; ++t) acc[p][t] = zero4();

    size_t arow = ((size_t)b * N_ + n0 + wn + li) * C_;
#pragma unroll 2
    for (int kb = 0; kb < 8; ++kb) {
        int kc = kb * 32 + 8 * lg;
        f16x8 ah = *(const f16x8*)&xh[arow + kc];
#pragma unroll
        for (int p = 0; p < 3; ++p)
#pragma unroll
            for (int t = 0; t < 4; ++t) {
                f16x8 bw = *(const f16x8*)&wf[(size_t)p * 32768
                               + (size_t)((ihb + t) * 16 + li) * C_ + kc];
                acc[p][t] = mfma16h(ah, bw, acc[p][t]);
            }
    }
    f16* g2p = (f16*)(ws + G2_F);
    f16* thp = (f16*)(ws + TH_F);
    f16* php = (f16*)(ws + PH_F);
#pragma unroll
    for (int p = 0; p < 3; ++p) {
        const float* bias = (p == 0) ? bg : (p == 1) ? bth : bph;
#pragma unroll
        for (int t = 0; t < 4; ++t) {
            int i = (ihb + t) * 16 + li;
            float bs = bias[i];
#pragma unroll
            for (int r = 0; r < 4; ++r) {
                int n = n0 + wn + 4 * lg + r;
                float v = acc[p][t][r] + bs;
                if (p == 0)
                    g2p[(((size_t)b * (N_ / 4) + (n >> 2)) * I_ + i) * 4 + (n & 3)] = (f16)v;
                else if (p == 1)
                    thp[((size_t)b * N_ + n) * I_ + i] = (f16)(v * LOG2E);  // base-2 logits
                else
                    php[((size_t)b * N_ + n) * I_ + i] = (f16)v;
            }
        }
    }
}

// ---------------- kernel 3: flash attention, 32 q/wave, KVB=32 ---------------
// grid (32 qtiles, B, splits), 256 thr = 4 waves. Each wave: two 16-q subtiles
// sharing every phi/g LDS read (halves LDS bytes per output). Swapped QK^T ->
// P lane-local; PV in-register with consistent k-slot map. exp2 domain.
__global__ __launch_bounds__(256, 3) void k_attn(ushort_t* ws, float* lse, int splits) {
    __shared__ __align__(16) ushort_t smem[16384];  // 32KB: phi@0(+4096), g@8192(+4096)
    int b = blockIdx.y, sp = blockIdx.z;
    int w = threadIdx.x >> 6, l = threadIdx.x & 63;
    int li = l & 15, lg = l >> 4;
    int q0 = blockIdx.x * 128 + w * 16;             // subtile A; subtile B at +64
    const f16* th = (const f16*)(ws + TH_F);
    const f16* ph = (const f16*)(ws + PH_F);
    const f16* g2 = (const f16*)(ws + G2_F);
    f16* yp = (f16*)(ws + YP_F) + (size_t)sp * ((size_t)B_ * N_ * I_);

    f16x8 qA[4], qB[4];
#pragma unroll
    for (int kb = 0; kb < 4; ++kb) {
        qA[kb] = *(const f16x8*)&th[((size_t)b * N_ + q0 + li) * I_ + kb * 32 + 8 * lg];
        qB[kb] = *(const f16x8*)&th[((size_t)b * N_ + q0 + 64 + li) * I_ + kb * 32 + 8 * lg];
    }

    f32x4 yA[8], yB[8];
#pragma unroll
    for (int dt = 0; dt < 8; ++dt) { yA[dt] = zero4(); yB[dt] = zero4(); }
    float mA = -1e30f, lA = 0.f, mB = -1e30f, lB = 0.f;

    int kvper = N_ / splits;
    int kv_beg = sp * kvper, nit = kvper / KVB;
    int srow = l >> 4;
    size_t sp0 = ((size_t)b * N_ + w * 8 + srow) * I_ + ((l & 15) ^ srow) * 8;
    size_t sp1 = ((size_t)b * N_ + w * 8 + 4 + srow) * I_ + (((l & 15) ^ srow) ^ 4) * 8;
    size_t sg0 = ((size_t)b * (N_ / 4) + w * 2) * 512 + l * 8;

    auto stage = [&](int kv0, int bufsel) {
        int bo = bufsel * 4096;
        gload_lds16(ph + (size_t)kv0 * I_ + sp0, smem + bo + w * 1024);
        gload_lds16(ph + (size_t)kv0 * I_ + sp1, smem + bo + w * 1024 + 512);
        gload_lds16(g2 + (size_t)(kv0 >> 2) * 512 + sg0, smem + 8192 + bo + w * 1024);
        gload_lds16(g2 + (size_t)(kv0 >> 2) * 512 + sg0 + 512,
                    smem + 8192 + bo + w * 1024 + 512);
    };

    stage(kv_beg, 0);
    __syncthreads();

    for (int it = 0; it < nit; ++it) {
        int buf = it & 1;
        if (it + 1 < nit) stage(kv_beg + (it + 1) * KVB, buf ^ 1);
        const f16* pb = (const f16*)(smem + buf * 4096);
        const f16* gbf = (const f16*)(smem + 8192 + buf * 4096);

        // ---- QK^T: each phi fragment feeds BOTH q-subtiles ----
        f32x4 fA0 = zero4(), fA1 = zero4(), fB0 = zero4(), fB1 = zero4();
        __builtin_amdgcn_s_setprio(1);
#pragma unroll
        for (int kb = 0; kb < 4; ++kb) {
            int cc = ((kb * 4 + lg) ^ (li & 7)) * 8;
            f16x8 a0 = *(const f16x8*)&pb[li * 128 + cc];
            f16x8 a1 = *(const f16x8*)&pb[(16 + li) * 128 + cc];
            fA0 = mfma16h(a0, qA[kb], fA0);
            fB0 = mfma16h(a0, qB[kb], fB0);
            fA1 = mfma16h(a1, qA[kb], fA1);
            fB1 = mfma16h(a1, qB[kb], fB1);
        }
        __builtin_amdgcn_s_setprio(0);

        // ---- online softmax (base-2), set A ----
        float tmA = fmaxf(fmaxf(fmaxf(fA0[0], fA0[1]), fmaxf(fA0[2], fA0[3])),
                          fmaxf(fmaxf(fA1[0], fA1[1]), fmaxf(fA1[2], fA1[3])));
        tmA = fmaxf(tmA, __shfl_xor(tmA, 16));
        tmA = fmaxf(tmA, __shfl_xor(tmA, 32));
        if (__ballot(tmA > mA + 11.0f)) {          // defer-max (T13), ~8 nats
            float mn = fmaxf(mA, tmA);
            float sc = exp2_hw(mA - mn);
            lA *= sc; mA = mn;
            float s0 = __shfl(sc, 4 * lg + 0);
            float s1 = __shfl(sc, 4 * lg + 1);
            float s2 = __shfl(sc, 4 * lg + 2);
            float s3 = __shfl(sc, 4 * lg + 3);
#pragma unroll
            for (int dt = 0; dt < 8; ++dt) {
                yA[dt][0] *= s0; yA[dt][1] *= s1; yA[dt][2] *= s2; yA[dt][3] *= s3;
            }
        }
        float rsA = 0.f;
#pragma unroll
        for (int r = 0; r < 4; ++r) {
            fA0[r] = exp2_hw(fA0[r] - mA); rsA += fA0[r];
            fA1[r] = exp2_hw(fA1[r] - mA); rsA += fA1[r];
        }
        rsA += __shfl_xor(rsA, 16);
        rsA += __shfl_xor(rsA, 32);
        lA += rsA;
        union PU { f16x2 h2[4]; f16x8 v; };
        PU pA;
        pA.h2[0] = pkrtz(fA0[0], fA0[1]); pA.h2[1] = pkrtz(fA0[2], fA0[3]);
        pA.h2[2] = pkrtz(fA1[0], fA1[1]); pA.h2[3] = pkrtz(fA1[2], fA1[3]);

        // ---- set B ----
        float tmB = fmaxf(fmaxf(fmaxf(fB0[0], fB0[1]), fmaxf(fB0[2], fB0[3])),
                          fmaxf(fmaxf(fB1[0], fB1[1]), fmaxf(fB1[2], fB1[3])));
        tmB = fmaxf(tmB, __shfl_xor(tmB, 16));
        tmB = fmaxf(tmB, __shfl_xor(tmB, 32));
        if (__ballot(tmB > mB + 11.0f)) {
            float mn = fmaxf(mB, tmB);
            float sc = exp2_hw(mB - mn);
            lB *= sc; mB = mn;
            float s0 = __shfl(sc, 4 * lg + 0);
            float s1 = __shfl(sc, 4 * lg + 1);
            float s2 = __shfl(sc, 4 * lg + 2);
            float s3 = __shfl(sc, 4 * lg + 3);
#pragma unroll
            for (int dt = 0; dt < 8; ++dt) {
                yB[dt][0] *= s0; yB[dt][1] *= s1; yB[dt][2] *= s2; yB[dt][3] *= s3;
            }
        }
        float rsB = 0.f;
#pragma unroll
        for (int r = 0; r < 4; ++r) {
            fB0[r] = exp2_hw(fB0[r] - mB); rsB += fB0[r];
            fB1[r] = exp2_hw(fB1[r] - mB); rsB += fB1[r];
        }
        rsB += __shfl_xor(rsB, 16);
        rsB += __shfl_xor(rsB, 32);
        lB += rsB;
        PU pB;
        pB.h2[0] = pkrtz(fB0[0], fB0[1]); pB.h2[1] = pkrtz(fB0[2], fB0[3]);
        pB.h2[2] = pkrtz(fB1[0], fB1[1]); pB.h2[3] = pkrtz(fB1[2], fB1[3]);

        // ---- PV: each g fragment feeds BOTH q-subtiles ----
        __builtin_amdgcn_s_setprio(1);
#pragma unroll
        for (int dt = 0; dt < 8; ++dt) {
            int gi = (dt * 16 + li) * 4;
            uint2 ga = *(const uint2*)&gbf[lg * 512 + gi];
            uint2 gbv = *(const uint2*)&gbf[(4 + lg) * 512 + gi];
            union { uint_t u[4]; f16x8 v; } gu;
            gu.u[0] = ga.x; gu.u[1] = ga.y; gu.u[2] = gbv.x; gu.u[3] = gbv.y;
            yA[dt] = mfma16h(pA.v, gu.v, yA[dt]);
            yB[dt] = mfma16h(pB.v, gu.v, yB[dt]);
        }
        __builtin_amdgcn_s_setprio(0);
        __syncthreads();
    }

    // epilogue: normalized partials + base-2 lse
    {
        float inv = 1.0f / lA;
        float i0 = __shfl(inv, 4 * lg + 0);
        float i1 = __shfl(inv, 4 * lg + 1);
        float i2 = __shfl(inv, 4 * lg + 2);
        float i3 = __shfl(inv, 4 * lg + 3);
#pragma unroll
        for (int dt = 0; dt < 8; ++dt) {
            size_t base = ((size_t)b * N_ + q0 + 4 * lg) * I_ + dt * 16 + li;
            yp[base]          = (f16)(yA[dt][0] * i0);
            yp[base + I_]     = (f16)(yA[dt][1] * i1);
            yp[base + 2 * I_] = (f16)(yA[dt][2] * i2);
            yp[base + 3 * I_] = (f16)(yA[dt][3] * i3);
        }
    }
    {
        float inv = 1.0f / lB;
        float i0 = __shfl(inv, 4 * lg + 0);
        float i1 = __shfl(inv, 4 * lg + 1);
        float i2 = __shfl(inv, 4 * lg + 2);
        float i3 = __shfl(inv, 4 * lg + 3);
#pragma unroll
        for (int dt = 0; dt < 8; ++dt) {
            size_t base = ((size_t)b * N_ + q0 + 64 + 4 * lg) * I_ + dt * 16 + li;
            yp[base]          = (f16)(yB[dt][0] * i0);
            yp[base + I_]     = (f16)(yB[dt][1] * i1);
            yp[base + 2 * I_] = (f16)(yB[dt][2] * i2);
            yp[base + 3 * I_] = (f16)(yB[dt][3] * i3);
        }
    }
    if (l < 16) {
        lse[((size_t)sp * B_ + b) * N_ + q0 + l]      = mA + log2_hw(lA);
        lse[((size_t)sp * B_ + b) * N_ + q0 + 64 + l] = mB + log2_hw(lB);
    }
}

// ------- kernel 4: fused split-merge + output projection + residual ----------
// grid (64 ntiles, B), 512 thr. Phase 1: merge partials into LDS y tile
// (padded rows for conflict-free b128). Phase 2: 8 waves project 256c x 64n.
__global__ __launch_bounds__(512) void k_out(const float* x, const float* bW,
        const ushort_t* ws, const float* lse, float* out, int splits) {
    __shared__ __align__(16) f16 ylds[64 * 136];
    int b = blockIdx.y, n0 = blockIdx.x * 64;
    int tid = threadIdx.x;
    {
        int nn = tid >> 3, ig = tid & 7;
        size_t lrow = (size_t)b * N_ + n0 + nn;
        float mx = -1e30f;
        for (int s = 0; s < splits; ++s)
            mx = fmaxf(mx, lse[(size_t)s * (B_ * N_) + lrow]);
        float sum = 0.f;
        for (int s = 0; s < splits; ++s)
            sum += exp2_hw(lse[(size_t)s * (B_ * N_) + lrow] - mx);
        float inv = 1.0f / sum;
        float acc[16];
#pragma unroll
        for (int j = 0; j < 16; ++j) acc[j] = 0.f;
        const f16* ypb = (const f16*)(ws + YP_F);
        for (int s = 0; s < splits; ++s) {
            float wg = exp2_hw(lse[(size_t)s * (B_ * N_) + lrow] - mx) * inv;
            const f16* p = ypb + (size_t)s * ((size_t)B_ * N_ * I_) + lrow * I_ + ig * 16;
            f16x8 v0 = *(const f16x8*)p;
            f16x8 v1 = *(const f16x8*)(p + 8);
#pragma unroll
            for (int j = 0; j < 8; ++j) {
                acc[j]     += wg * (float)v0[j];
                acc[8 + j] += wg * (float)v1[j];
            }
        }
        f16 o[16];
#pragma unroll
        for (int j = 0; j < 16; ++j) o[j] = (f16)acc[j];
        *(uint4*)&ylds[nn * 136 + ig * 16]     = *(uint4*)&o[0];
        *(uint4*)&ylds[nn * 136 + ig * 16 + 8] = *(uint4*)&o[8];
    }
    __syncthreads();

    int w = tid >> 6, l = tid & 63;
    int li = l & 15, lg = l >> 4;
    int cw = (w >> 1) * 64, nh = (w & 1) * 32;
    const f16* wfp = (const f16*)(ws + W_F) + 98304;   // w_W [256][128] f16

    f32x4 acc2[4][2];
#pragma unroll
    for (int mm = 0; mm < 4; ++mm)
#pragma unroll
        for (int n = 0; n < 2; ++n) acc2[mm][n] = zero4();

#pragma unroll 2
    for (int kb = 0; kb < 4; ++kb) {
        int kc = kb * 32 + 8 * lg;
        f16x8 a[4], byv[2];
#pragma unroll
        for (int mm = 0; mm < 4; ++mm)
            a[mm] = *(const f16x8*)&wfp[(size_t)(cw + mm * 16 + li) * I_ + kc];
#pragma unroll
        for (int n = 0; n < 2; ++n)
            byv[n] = *(const f16x8*)&ylds[(nh + n * 16 + li) * 136 + kc];
#pragma unroll
        for (int mm = 0; mm < 4; ++mm)
#pragma unroll
            for (int n = 0; n < 2; ++n)
                acc2[mm][n] = mfma16h(a[mm], byv[n], acc2[mm][n]);
    }
#pragma unroll
    for (int mm = 0; mm < 4; ++mm)
#pragma unroll
        for (int n = 0; n < 2; ++n)
#pragma unroll
            for (int r = 0; r < 4; ++r) {
                int c = cw + mm * 16 + lg * 4 + r;
                int nn = n0 + nh + n * 16 + li;
                size_t xi = ((size_t)b * C_ + c) * N_ + nn;
                out[xi] = acc2[mm][n][r] + bW[c] + x[xi];
            }
}

extern "C" void kernel_launch(void* const* d_in, const int* in_sizes, int n_in,
                              void* d_out, int out_size, void* d_ws, size_t ws_size,
                              hipStream_t stream) {
    const float* x  = (const float*)d_in[0];
    const float* wg = (const float*)d_in[1];
    const float* bg = (const float*)d_in[2];
    const float* wt = (const float*)d_in[3];
    const float* bt = (const float*)d_in[4];
    const float* wp = (const float*)d_in[5];
    const float* bp = (const float*)d_in[6];
    const float* wW = (const float*)d_in[7];
    const float* bW = (const float*)d_in[8];
    ushort_t* ws = (ushort_t*)d_ws;
    float* out = (float*)d_out;

    // splits=8 needs ~55.3 MB of ws; fall back to 4 (38.3 MB, known good)
    int splits = (ws_size >= 55400000ull) ? 8 : 4;
    size_t lse_off = 2ull * (YP_F + (size_t)splits * 2097152ull);
    float* lse = (float*)((char*)d_ws + lse_off);

    k_transpose_x<<<dim3(66, 4, 4), 256, 0, stream>>>(x, wg, wt, wp, wW, ws);
    k_proj_all<<<dim3(64, 4), 512, 0, stream>>>(bg, bt, bp, ws);
    k_attn<<<dim3(32, 4, splits), 256, 0, stream>>>(ws, lse, splits);
    k_out<<<dim3(64, 4), 512, 0, stream>>>(x, bW, ws, lse, out, splits);
}

// Round 8
// 110.243 us; speedup vs baseline: 5.6000x; 1.0690x over previous
//
#include <hip/hip_runtime.h>

typedef unsigned short ushort_t;
typedef unsigned int uint_t;
typedef _Float16 f16;
typedef __attribute__((ext_vector_type(8))) _Float16 f16x8;
typedef __attribute__((ext_vector_type(2))) _Float16 f16x2;
typedef __attribute__((ext_vector_type(4))) float f32x4;

#define B_ 4
#define C_ 256
#define I_ 128
#define N_ 4096
#define KVB 32
#define TOT_IT (N_ / KVB)     // 128
#define LOG2E 1.44269504f

// ws layout in 2-byte units
#define XT_F 0ull             // f16 x_t [B][N][C] (4,194,304); later YP splits 0,1
#define W_F  4194304ull       // f16 weights: wg@0 wt@32768 wp@65536 wW@98304
#define TH_F 4325376ull       // f16 theta (pre-scaled by log2e) [B][N][I]
#define PH_F 6422528ull       // f16 phi [B][N][I]
#define G3_F 8519680ull       // f16 g, PV-tile layout [B][N/32][4][I][8], lg-XOR swz
#define YPX_F 10616832ull     // f16 partials for splits >= 2 (2,097,152 each)
// lse (f32, base-2) at byte offset 2*(YPX_F + (S-2)*2097152)

__device__ __forceinline__ float exp2_hw(float x) { return __builtin_amdgcn_exp2f(x); }
__device__ __forceinline__ float log2_hw(float x) { return __builtin_amdgcn_logf(x); }

__device__ __forceinline__ f16x2 pkrtz(float a, float b) {
    auto r = __builtin_amdgcn_cvt_pkrtz(a, b);
    f16x2 o;
    __builtin_memcpy(&o, &r, sizeof(o));
    return o;
}
__device__ __forceinline__ f32x4 mfma16h(f16x8 a, f16x8 b, f32x4 c) {
    return __builtin_amdgcn_mfma_f32_16x16x32_f16(a, b, c, 0, 0, 0);
}
__device__ __forceinline__ f32x4 zero4() { f32x4 z = {0.f, 0.f, 0.f, 0.f}; return z; }
__device__ __forceinline__ void gload_lds16(const void* g, void* lds) {
    __builtin_amdgcn_global_load_lds(
        (const __attribute__((address_space(1))) void*)g,
        (__attribute__((address_space(3))) void*)lds, 16, 0, 0);
}
// partial-y buffer for split s (f16 units into ws)
__device__ __forceinline__ size_t yp_off(int s) {
    return (s < 2) ? (size_t)s * 2097152ull
                   : YPX_F + (size_t)(s - 2) * 2097152ull;
}

// ------- kernel 1: transpose+convert x -> x_t f16; fused weight convert ------
__global__ __launch_bounds__(256) void k_transpose_x(const float* x, const float* wg,
        const float* wt, const float* wp, const float* wW, ushort_t* ws) {
    if (blockIdx.x >= 64) {
        int idx = (((blockIdx.x - 64) * 16 + blockIdx.y * 4 + blockIdx.z) * 256
                   + threadIdx.x) * 16;
        const float* src;
        int off;
        if (idx < 32768)      { src = wg; off = idx; }
        else if (idx < 65536) { src = wt; off = idx - 32768; }
        else if (idx < 98304) { src = wp; off = idx - 65536; }
        else                  { src = wW; off = idx - 98304; }
        f16 o[16];
#pragma unroll
        for (int j = 0; j < 16; ++j) o[j] = (f16)src[off + j];
        f16* wd = (f16*)(ws + W_F);
        *(uint4*)&wd[idx]     = *(uint4*)&o[0];
        *(uint4*)&wd[idx + 8] = *(uint4*)&o[8];
        return;
    }
    __shared__ float t[64][65];
    int b = blockIdx.z, c0 = blockIdx.y * 64, n0 = blockIdx.x * 64;
    int tid = threadIdx.x;
    int cl = tid & 63, ng = tid >> 6;
    const float* xp = x + ((size_t)(b * C_ + c0 + cl)) * N_ + n0 + ng * 16;
#pragma unroll
    for (int j = 0; j < 4; ++j) {
        float4 v = ((const float4*)xp)[j];
        t[cl][ng * 16 + j * 4 + 0] = v.x;
        t[cl][ng * 16 + j * 4 + 1] = v.y;
        t[cl][ng * 16 + j * 4 + 2] = v.z;
        t[cl][ng * 16 + j * 4 + 3] = v.w;
    }
    __syncthreads();
    // coalesced writes: 4 consecutive threads cover one n-row's 64 c (128B)
    int cg4 = tid & 3, nr = tid >> 2;
    f16 hv[16];
#pragma unroll
    for (int k = 0; k < 16; ++k) hv[k] = (f16)t[cg4 * 16 + k][nr];
    size_t dst = ((size_t)b * N_ + n0 + nr) * C_ + c0 + cg4 * 16;
    f16* xd = (f16*)(ws + XT_F);
    *(uint4*)&xd[dst]     = *(uint4*)&hv[0];
    *(uint4*)&xd[dst + 8] = *(uint4*)&hv[8];
}

// -------- kernel 2: fused theta/phi/g projections (single-f16 x) -------------
__global__ __launch_bounds__(512) void k_proj_all(const float* bg, const float* bth,
                                                  const float* bph, ushort_t* ws) {
    int b = blockIdx.y, n0 = blockIdx.x * 64;
    int w = threadIdx.x >> 6, l = threadIdx.x & 63;
    int li = l & 15, lg = l >> 4;
    int wn = (w & 3) * 16;
    int ihb = (w >> 2) * 4;
    const f16* xh = (const f16*)(ws + XT_F);
    const f16* wf = (const f16*)(ws + W_F);

    f32x4 acc[3][4];
#pragma unroll
    for (int p = 0; p < 3; ++p)
#pragma unroll
        for (int t = 0; t < 4; ++t) acc[p][t] = zero4();

    size_t arow = ((size_t)b * N_ + n0 + wn + li) * C_;
#pragma unroll 2
    for (int kb = 0; kb < 8; ++kb) {
        int kc = kb * 32 + 8 * lg;
        f16x8 ah = *(const f16x8*)&xh[arow + kc];
#pragma unroll
        for (int p = 0; p < 3; ++p)
#pragma unroll
            for (int t = 0; t < 4; ++t) {
                f16x8 bw = *(const f16x8*)&wf[(size_t)p * 32768
                               + (size_t)((ihb + t) * 16 + li) * C_ + kc];
                acc[p][t] = mfma16h(ah, bw, acc[p][t]);
            }
    }
    f16* g3p = (f16*)(ws + G3_F);
    f16* thp = (f16*)(ws + TH_F);
    f16* php = (f16*)(ws + PH_F);
#pragma unroll
    for (int p = 0; p < 3; ++p) {
        const float* bias = (p == 0) ? bg : (p == 1) ? bth : bph;
#pragma unroll
        for (int t = 0; t < 4; ++t) {
            int i = (ihb + t) * 16 + li;
            float bs = bias[i];
#pragma unroll
            for (int r = 0; r < 4; ++r) {
                int n = n0 + wn + 4 * lg + r;
                float v = acc[p][t][r] + bs;
                if (p == 0) {
                    int tq = (n >> 2) & 3;    // lg quad-row within PV tile
                    size_t gi = ((size_t)b * (N_ / 32) + (n >> 5)) * 4096
                              + (size_t)(tq * 128 + (i ^ (tq << 1))) * 8
                              + ((n >> 4) & 1) * 4 + (n & 3);
                    g3p[gi] = (f16)v;
                } else if (p == 1)
                    thp[((size_t)b * N_ + n) * I_ + i] = (f16)(v * LOG2E);
                else
                    php[((size_t)b * N_ + n) * I_ + i] = (f16)v;
            }
        }
    }
}

// ---------------- kernel 3: flash attention, 32 q/wave, KVB=32 ---------------
// grid (32 qtiles, B, splits), 256 thr = 4 waves. Two 16-q subtiles per wave
// share every phi/g LDS read. Swapped QK^T -> P lane-local; PV via one
// ds_read_b128 per dt (G3 layout, lg-XOR swizzled). exp2 domain. Per-lane
// partial softmax-sum (cross-lane reduce deferred to epilogue).
__global__ __launch_bounds__(256, 3) void k_attn(ushort_t* ws, float* lse, int splits) {
    __shared__ __align__(16) ushort_t smem[16384];  // 32KB: phi@0(+4096), g@8192(+4096)
    int b = blockIdx.y, sp = blockIdx.z;
    int w = threadIdx.x >> 6, l = threadIdx.x & 63;
    int li = l & 15, lg = l >> 4;
    int q0 = blockIdx.x * 128 + w * 16;             // subtile A; subtile B at +64
    const f16* th = (const f16*)(ws + TH_F);
    const f16* ph = (const f16*)(ws + PH_F);
    const f16* g3 = (const f16*)(ws + G3_F);
    f16* yp = (f16*)ws + yp_off(sp);

    f16x8 qA[4], qB[4];
#pragma unroll
    for (int kb = 0; kb < 4; ++kb) {
        qA[kb] = *(const f16x8*)&th[((size_t)b * N_ + q0 + li) * I_ + kb * 32 + 8 * lg];
        qB[kb] = *(const f16x8*)&th[((size_t)b * N_ + q0 + 64 + li) * I_ + kb * 32 + 8 * lg];
    }

    f32x4 yA[8], yB[8];
#pragma unroll
    for (int dt = 0; dt < 8; ++dt) { yA[dt] = zero4(); yB[dt] = zero4(); }
    float mA = -1e30f, lA = 0.f, mB = -1e30f, lB = 0.f;

    int beg = (sp * TOT_IT) / splits;
    int end = ((sp + 1) * TOT_IT) / splits;
    int nit = end - beg;
    int srow = l >> 4;
    size_t sp0 = ((size_t)b * N_ + w * 8 + srow) * I_ + ((l & 15) ^ srow) * 8;
    size_t sp1 = ((size_t)b * N_ + w * 8 + 4 + srow) * I_ + (((l & 15) ^ srow) ^ 4) * 8;
    size_t sg0 = (size_t)b * (N_ / 32) * 4096 + w * 1024 + l * 8;

    auto stage = [&](int kv0, int bufsel) {
        int bo = bufsel * 4096;
        gload_lds16(ph + (size_t)kv0 * I_ + sp0, smem + bo + w * 1024);
        gload_lds16(ph + (size_t)kv0 * I_ + sp1, smem + bo + w * 1024 + 512);
        gload_lds16(g3 + sg0 + (size_t)kv0 * 128, smem + 8192 + bo + w * 1024);
        gload_lds16(g3 + sg0 + (size_t)kv0 * 128 + 512,
                    smem + 8192 + bo + w * 1024 + 512);
    };

    stage(beg * KVB, 0);
    __syncthreads();

    for (int it = 0; it < nit; ++it) {
        int buf = it & 1;
        if (it + 1 < nit) stage((beg + it + 1) * KVB, buf ^ 1);
        const f16* pb = (const f16*)(smem + buf * 4096);
        const f16* gbf = (const f16*)(smem + 8192 + buf * 4096);

        // ---- QK^T: each phi fragment feeds BOTH q-subtiles ----
        f32x4 fA0 = zero4(), fA1 = zero4(), fB0 = zero4(), fB1 = zero4();
        __builtin_amdgcn_s_setprio(1);
#pragma unroll
        for (int kb = 0; kb < 4; ++kb) {
            int cc = ((kb * 4 + lg) ^ (li & 7)) * 8;
            f16x8 a0 = *(const f16x8*)&pb[li * 128 + cc];
            f16x8 a1 = *(const f16x8*)&pb[(16 + li) * 128 + cc];
            fA0 = mfma16h(a0, qA[kb], fA0);
            fB0 = mfma16h(a0, qB[kb], fB0);
            fA1 = mfma16h(a1, qA[kb], fA1);
            fB1 = mfma16h(a1, qB[kb], fB1);
        }
        __builtin_amdgcn_s_setprio(0);

        // ---- online softmax (base-2), set A: max-reduce only ----
        float tmA = fmaxf(fmaxf(fmaxf(fA0[0], fA0[1]), fmaxf(fA0[2], fA0[3])),
                          fmaxf(fmaxf(fA1[0], fA1[1]), fmaxf(fA1[2], fA1[3])));
        tmA = fmaxf(tmA, __shfl_xor(tmA, 16));
        tmA = fmaxf(tmA, __shfl_xor(tmA, 32));
        if (__ballot(tmA > mA + 11.0f)) {          // defer-max (T13)
            float mn = fmaxf(mA, tmA);
            float sc = exp2_hw(mA - mn);
            lA *= sc; mA = mn;
            float s0 = __shfl(sc, 4 * lg + 0);
            float s1 = __shfl(sc, 4 * lg + 1);
            float s2 = __shfl(sc, 4 * lg + 2);
            float s3 = __shfl(sc, 4 * lg + 3);
#pragma unroll
            for (int dt = 0; dt < 8; ++dt) {
                yA[dt][0] *= s0; yA[dt][1] *= s1; yA[dt][2] *= s2; yA[dt][3] *= s3;
            }
        }
#pragma unroll
        for (int r = 0; r < 4; ++r) {
            fA0[r] = exp2_hw(fA0[r] - mA); lA += fA0[r];
            fA1[r] = exp2_hw(fA1[r] - mA); lA += fA1[r];
        }
        union PU { f16x2 h2[4]; f16x8 v; };
        PU pA;
        pA.h2[0] = pkrtz(fA0[0], fA0[1]); pA.h2[1] = pkrtz(fA0[2], fA0[3]);
        pA.h2[2] = pkrtz(fA1[0], fA1[1]); pA.h2[3] = pkrtz(fA1[2], fA1[3]);

        // ---- set B ----
        float tmB = fmaxf(fmaxf(fmaxf(fB0[0], fB0[1]), fmaxf(fB0[2], fB0[3])),
                          fmaxf(fmaxf(fB1[0], fB1[1]), fmaxf(fB1[2], fB1[3])));
        tmB = fmaxf(tmB, __shfl_xor(tmB, 16));
        tmB = fmaxf(tmB, __shfl_xor(tmB, 32));
        if (__ballot(tmB > mB + 11.0f)) {
            float mn = fmaxf(mB, tmB);
            float sc = exp2_hw(mB - mn);
            lB *= sc; mB = mn;
            float s0 = __shfl(sc, 4 * lg + 0);
            float s1 = __shfl(sc, 4 * lg + 1);
            float s2 = __shfl(sc, 4 * lg + 2);
            float s3 = __shfl(sc, 4 * lg + 3);
#pragma unroll
            for (int dt = 0; dt < 8; ++dt) {
                yB[dt][0] *= s0; yB[dt][1] *= s1; yB[dt][2] *= s2; yB[dt][3] *= s3;
            }
        }
#pragma unroll
        for (int r = 0; r < 4; ++r) {
            fB0[r] = exp2_hw(fB0[r] - mB); lB += fB0[r];
            fB1[r] = exp2_hw(fB1[r] - mB); lB += fB1[r];
        }
        PU pB;
        pB.h2[0] = pkrtz(fB0[0], fB0[1]); pB.h2[1] = pkrtz(fB0[2], fB0[3]);
        pB.h2[2] = pkrtz(fB1[0], fB1[1]); pB.h2[3] = pkrtz(fB1[2], fB1[3]);

        // ---- PV: one b128 g fragment per dt feeds BOTH q-subtiles ----
        __builtin_amdgcn_s_setprio(1);
#pragma unroll
        for (int dt = 0; dt < 8; ++dt) {
            int i = dt * 16 + li;
            f16x8 gv = *(const f16x8*)&gbf[(size_t)(lg * 128 + (i ^ (lg << 1))) * 8];
            yA[dt] = mfma16h(pA.v, gv, yA[dt]);
            yB[dt] = mfma16h(pB.v, gv, yB[dt]);
        }
        __builtin_amdgcn_s_setprio(0);
        __syncthreads();
    }

    // epilogue: cross-lane sum (deferred), normalized partials + base-2 lse
    lA += __shfl_xor(lA, 16); lA += __shfl_xor(lA, 32);
    lB += __shfl_xor(lB, 16); lB += __shfl_xor(lB, 32);
    {
        float inv = 1.0f / lA;
        float i0 = __shfl(inv, 4 * lg + 0);
        float i1 = __shfl(inv, 4 * lg + 1);
        float i2 = __shfl(inv, 4 * lg + 2);
        float i3 = __shfl(inv, 4 * lg + 3);
#pragma unroll
        for (int dt = 0; dt < 8; ++dt) {
            size_t base = ((size_t)b * N_ + q0 + 4 * lg) * I_ + dt * 16 + li;
            yp[base]          = (f16)(yA[dt][0] * i0);
            yp[base + I_]     = (f16)(yA[dt][1] * i1);
            yp[base + 2 * I_] = (f16)(yA[dt][2] * i2);
            yp[base + 3 * I_] = (f16)(yA[dt][3] * i3);
        }
    }
    {
        float inv = 1.0f / lB;
        float i0 = __shfl(inv, 4 * lg + 0);
        float i1 = __shfl(inv, 4 * lg + 1);
        float i2 = __shfl(inv, 4 * lg + 2);
        float i3 = __shfl(inv, 4 * lg + 3);
#pragma unroll
        for (int dt = 0; dt < 8; ++dt) {
            size_t base = ((size_t)b * N_ + q0 + 64 + 4 * lg) * I_ + dt * 16 + li;
            yp[base]          = (f16)(yB[dt][0] * i0);
            yp[base + I_]     = (f16)(yB[dt][1] * i1);
            yp[base + 2 * I_] = (f16)(yB[dt][2] * i2);
            yp[base + 3 * I_] = (f16)(yB[dt][3] * i3);
        }
    }
    if (l < 16) {
        lse[((size_t)sp * B_ + b) * N_ + q0 + l]      = mA + log2_hw(lA);
        lse[((size_t)sp * B_ + b) * N_ + q0 + 64 + l] = mB + log2_hw(lB);
    }
}

// ------- kernel 4: fused split-merge + output projection + residual ----------
__global__ __launch_bounds__(512) void k_out(const float* x, const float* bW,
        const ushort_t* ws, const float* lse, float* out, int splits) {
    __shared__ __align__(16) f16 ylds[64 * 136];
    int b = blockIdx.y, n0 = blockIdx.x * 64;
    int tid = threadIdx.x;
    {
        int nn = tid >> 3, ig = tid & 7;
        size_t lrow = (size_t)b * N_ + n0 + nn;
        float mx = -1e30f;
        for (int s = 0; s < splits; ++s)
            mx = fmaxf(mx, lse[(size_t)s * (B_ * N_) + lrow]);
        float sum = 0.f;
        for (int s = 0; s < splits; ++s)
            sum += exp2_hw(lse[(size_t)s * (B_ * N_) + lrow] - mx);
        float inv = 1.0f / sum;
        float acc[16];
#pragma unroll
        for (int j = 0; j < 16; ++j) acc[j] = 0.f;
        for (int s = 0; s < splits; ++s) {
            float wg = exp2_hw(lse[(size_t)s * (B_ * N_) + lrow] - mx) * inv;
            const f16* p = (const f16*)ws + yp_off(s) + lrow * I_ + ig * 16;
            f16x8 v0 = *(const f16x8*)p;
            f16x8 v1 = *(const f16x8*)(p + 8);
#pragma unroll
            for (int j = 0; j < 8; ++j) {
                acc[j]     += wg * (float)v0[j];
                acc[8 + j] += wg * (float)v1[j];
            }
        }
        f16 o[16];
#pragma unroll
        for (int j = 0; j < 16; ++j) o[j] = (f16)acc[j];
        *(uint4*)&ylds[nn * 136 + ig * 16]     = *(uint4*)&o[0];
        *(uint4*)&ylds[nn * 136 + ig * 16 + 8] = *(uint4*)&o[8];
    }
    __syncthreads();

    int w = tid >> 6, l = tid & 63;
    int li = l & 15, lg = l >> 4;
    int cw = (w >> 1) * 64, nh = (w & 1) * 32;
    const f16* wfp = (const f16*)(ws + W_F) + 98304;   // w_W [256][128] f16

    f32x4 acc2[4][2];
#pragma unroll
    for (int mm = 0; mm < 4; ++mm)
#pragma unroll
        for (int n = 0; n < 2; ++n) acc2[mm][n] = zero4();

#pragma unroll 2
    for (int kb = 0; kb < 4; ++kb) {
        int kc = kb * 32 + 8 * lg;
        f16x8 a[4], byv[2];
#pragma unroll
        for (int mm = 0; mm < 4; ++mm)
            a[mm] = *(const f16x8*)&wfp[(size_t)(cw + mm * 16 + li) * I_ + kc];
#pragma unroll
        for (int n = 0; n < 2; ++n)
            byv[n] = *(const f16x8*)&ylds[(nh + n * 16 + li) * 136 + kc];
#pragma unroll
        for (int mm = 0; mm < 4; ++mm)
#pragma unroll
            for (int n = 0; n < 2; ++n)
                acc2[mm][n] = mfma16h(a[mm], byv[n], acc2[mm][n]);
    }
#pragma unroll
    for (int mm = 0; mm < 4; ++mm)
#pragma unroll
        for (int n = 0; n < 2; ++n)
#pragma unroll
            for (int r = 0; r < 4; ++r) {
                int c = cw + mm * 16 + lg * 4 + r;
                int nn = n0 + nh + n * 16 + li;
                size_t xi = ((size_t)b * C_ + c) * N_ + nn;
                out[xi] = acc2[mm][n][r] + bW[c] + x[xi];
            }
}

extern "C" void kernel_launch(void* const* d_in, const int* in_sizes, int n_in,
                              void* d_out, int out_size, void* d_ws, size_t ws_size,
                              hipStream_t stream) {
    const float* x  = (const float*)d_in[0];
    const float* wg = (const float*)d_in[1];
    const float* bg = (const float*)d_in[2];
    const float* wt = (const float*)d_in[3];
    const float* bt = (const float*)d_in[4];
    const float* wp = (const float*)d_in[5];
    const float* bp = (const float*)d_in[6];
    const float* wW = (const float*)d_in[7];
    const float* bW = (const float*)d_in[8];
    ushort_t* ws = (ushort_t*)d_ws;
    float* out = (float*)d_out;

    // footprint(S) = 2*(YPX_F + (S-2)*2097152) + S*65536 bytes
    int splits = (ws_size >= 46923776ull) ? 8
               : (ws_size >= 38404096ull) ? 6 : 4;
    size_t lse_off = 2ull * (YPX_F + (size_t)(splits - 2) * 2097152ull);
    float* lse = (float*)((char*)d_ws + lse_off);

    k_transpose_x<<<dim3(66, 4, 4), 256, 0, stream>>>(x, wg, wt, wp, wW, ws);
    k_proj_all<<<dim3(64, 4), 512, 0, stream>>>(bg, bt, bp, ws);
    k_attn<<<dim3(32, 4, splits), 256, 0, stream>>>(ws, lse, splits);
    k_out<<<dim3(64, 4), 512, 0, stream>>>(x, bW, ws, lse, out, splits);
}